// Round 2
// baseline (779.100 us; speedup 1.0000x reference)
//
#include <hip/hip_runtime.h>
#include <hip/hip_bf16.h>
#include <math.h>

#define D_MODEL 384
#define D_STATE 64
#define D_INNER 768
#define HEADDIM 96
#define NHEADS 8
#define CONV_DIM 896
#define D_IN_PROJ 1672
#define ZXB_LD 1664        /* bf16 zx row stride (z,X,B,C); dt split to fp32 */
#define BATCH 8
#define SEQ 1024
#define ROWS (BATCH*SEQ)   /* 8192 */
#define NUM_LAYERS 6
#define NC 32              /* chunks */
#define CHUNK 32           /* timesteps per chunk */
#define NPAD_IN 1792       /* 14 * 128 */
#define NPAD_OUT 384       /* 3 * 128  */
#define VP 776             /* padded Vsh row (shorts) */

typedef __hip_bfloat16 bf16;
using bf16x8_t = __attribute__((ext_vector_type(8))) short;
using f32x4_t  = __attribute__((ext_vector_type(4))) float;

__device__ __forceinline__ float softplus_f(float v){
  return v > 20.f ? v : log1pf(expf(v));
}
__device__ __forceinline__ float silu_f(float v){
  return v / (1.f + expf(-v));
}
__device__ __forceinline__ float bits_to_f(unsigned short u){
  union{unsigned u32; float f;} cv; cv.u32 = ((unsigned)u)<<16; return cv.f;
}
__device__ __forceinline__ unsigned short f_to_bits(float f){
  union{bf16 b; unsigned short u;} cv; cv.b = __float2bfloat16(f); return cv.u;
}

/* ------- weight transpose + fp32->bf16, all layers batched via grid.z ---------- */
__global__ void wconv_kernel(const float* __restrict__ W, bf16* __restrict__ Wt,
                             int K, int N, int Npad){
  __shared__ float tile[32][33];
  W  += (size_t)blockIdx.z*K*N;
  Wt += (size_t)blockIdx.z*Npad*K;
  int kb = blockIdx.y*32, nb = blockIdx.x*32;
  int tx = threadIdx.x, ty = threadIdx.y;   /* 32 x 8 */
  #pragma unroll
  for (int r=0;r<32;r+=8){
    int k = kb+ty+r, n = nb+tx;
    tile[ty+r][tx] = (k<K && n<N) ? W[(size_t)k*N+n] : 0.f;
  }
  __syncthreads();
  #pragma unroll
  for (int r=0;r<32;r+=8){
    int n = nb+ty+r, k = kb+tx;
    if (n<Npad && k<K) Wt[(size_t)n*K+k] = __float2bfloat16(tile[tx][ty+r]);
  }
}

/* ---------------- LayerNorm: one WAVE (64 ln) per row of 384 -> bf16 ----------- */
__global__ __launch_bounds__(256) void ln_kernel(const float* __restrict__ x, const float* __restrict__ w,
                          const float* __restrict__ b, bf16* __restrict__ o){
  const int wave = threadIdx.x >> 6, lane = threadIdx.x & 63;
  const int r = blockIdx.x*4 + wave;
  const float* xr = x + (size_t)r*D_MODEL;
  float2 v[3];
  float s = 0.f, sq = 0.f;
  #pragma unroll
  for (int e=0;e<3;e++){
    v[e] = *(const float2*)(xr + e*128 + lane*2);
    s  += v[e].x + v[e].y;
    sq += v[e].x*v[e].x + v[e].y*v[e].y;
  }
  #pragma unroll
  for (int off=1; off<64; off<<=1){
    s  += __shfl_xor(s, off);
    sq += __shfl_xor(sq, off);
  }
  float mu  = s*(1.f/D_MODEL);
  float var = sq*(1.f/D_MODEL) - mu*mu;
  var = var < 0.f ? 0.f : var;
  float rstd = rsqrtf(var + 1e-12f);
  unsigned short* orow = (unsigned short*)o + (size_t)r*D_MODEL;
  #pragma unroll
  for (int e=0;e<3;e++){
    int c = e*128 + lane*2;
    float2 wv = *(const float2*)(w + c);
    float2 bv = *(const float2*)(b + c);
    ushort2 ov;
    ov.x = f_to_bits((v[e].x-mu)*rstd*wv.x + bv.x);
    ov.y = f_to_bits((v[e].y-mu)*rstd*wv.y + bv.y);
    *(ushort2*)(orow + c) = ov;
  }
}

/* ------- bf16 MFMA GEMM (in-proj): bf16 zxb out + fp32 dtraw --------------------
   128x128 tile; XCD-swizzled so same-M blocks share an XCD L2 (A fetched once). */
__global__ __launch_bounds__(256) void gemm_in(
    const unsigned short* __restrict__ A,   /* M x K bf16, row-major */
    const unsigned short* __restrict__ Bt,  /* Npad x K bf16 (B transposed) */
    unsigned short* __restrict__ Cbf,       /* M x ZXB_LD bf16 */
    float* __restrict__ dtraw,              /* M x 8 fp32 */
    int K){
  __shared__ __align__(16) unsigned short smem[128*136];  /* 34 KB */
  unsigned short* As = smem;          /* 128*32 */
  unsigned short* Bs = smem + 4096;   /* 128*32 */
  const int tid = threadIdx.x;
  const int wave = tid >> 6, lane = tid & 63;
  const int lq = lane >> 4, lm = lane & 15;
  /* XCD swizzle: 896 blocks = 8 XCDs x 112; each XCD gets 8 full M-rows */
  const int lin = blockIdx.y*14 + blockIdx.x;
  const int nl  = (lin & 7)*112 + (lin >> 3);
  const int m0 = (nl / 14) * 128, n0 = (nl % 14) * 128;
  const int wm = (wave >> 1) * 64, wn = (wave & 1) * 64;
  f32x4_t acc[4][4];
  #pragma unroll
  for (int i=0;i<4;i++)
    #pragma unroll
    for (int j=0;j<4;j++)
      acc[i][j] = (f32x4_t){0.f,0.f,0.f,0.f};

  for (int k0 = 0; k0 < K; k0 += 32){
    if (k0) __syncthreads();
    #pragma unroll
    for (int q=0;q<2;q++){
      int o = q*4096 + wave*1024 + lane*16;
      int m = o >> 6;
      int kb = o & 63;
      const unsigned short* ga = A  + (size_t)(m0+m)*K + k0 + (kb>>1);
      __builtin_amdgcn_global_load_lds(
          (const __attribute__((address_space(1))) void*)ga,
          (__attribute__((address_space(3))) void*)((char*)As + o), 16, 0, 0);
      const unsigned short* gb = Bt + (size_t)(n0+m)*K + k0 + (kb>>1);
      __builtin_amdgcn_global_load_lds(
          (const __attribute__((address_space(1))) void*)gb,
          (__attribute__((address_space(3))) void*)((char*)Bs + o), 16, 0, 0);
    }
    __syncthreads();
    bf16x8_t af[4], bfv[4];
    #pragma unroll
    for (int i=0;i<4;i++)
      af[i]  = *(const bf16x8_t*)(As + (wm + i*16 + lm)*32 + lq*8);
    #pragma unroll
    for (int j=0;j<4;j++)
      bfv[j] = *(const bf16x8_t*)(Bs + (wn + j*16 + lm)*32 + lq*8);
    #pragma unroll
    for (int i=0;i<4;i++)
      #pragma unroll
      for (int j=0;j<4;j++)
        acc[i][j] = __builtin_amdgcn_mfma_f32_16x16x32_bf16(af[i], bfv[j], acc[i][j], 0, 0, 0);
  }

  if (n0 == ZXB_LD){
    /* dt block: local cols 0..7 are dt (fp32 direct); rest is padding */
    if ((wave & 1) == 0 && lm < 8){
      #pragma unroll
      for (int i=0;i<4;i++){
        int row = m0 + wm + i*16 + lq*4;
        #pragma unroll
        for (int r=0;r<4;r++)
          dtraw[(size_t)(row+r)*8 + lm] = acc[i][0][r];
      }
    }
    return;
  }
  __syncthreads();   /* done reading As/Bs: reuse smem as C-stage */
  #pragma unroll
  for (int i=0;i<4;i++){
    int rl = wm + i*16 + lq*4;
    #pragma unroll
    for (int j=0;j<4;j++){
      int cl = wn + j*16 + lm;
      #pragma unroll
      for (int r=0;r<4;r++)
        smem[(rl+r)*136 + cl] = f_to_bits(acc[i][j][r]);
    }
  }
  __syncthreads();
  /* 2 threads/row, 8x 16B stores each */
  {
    int row = tid >> 1;
    int cbase = (tid & 1) * 64;
    size_t gb = (size_t)(m0 + row) * ZXB_LD + n0 + cbase;
    #pragma unroll
    for (int k=0;k<8;k++)
      *(bf16x8_t*)(Cbf + gb + k*8) = *(const bf16x8_t*)&smem[row*136 + cbase + k*8];
  }
}

/* ------- bf16 MFMA GEMM (out-proj): 64x128 tile, 384 blocks, fp32 += ----------- */
__global__ __launch_bounds__(256) void gemm_out(
    const unsigned short* __restrict__ A,   /* M x K bf16, row-major */
    const unsigned short* __restrict__ Bt,  /* N x K bf16 (B transposed) */
    float* __restrict__ Cf,                 /* M x ldc fp32 (accumulate) */
    int K, int ldc){
  __shared__ __align__(16) unsigned short smem[16896];  /* 33 KB: 12KB stage / 64x132 f32 epi */
  const int tid = threadIdx.x;
  const int wave = tid >> 6, lane = tid & 63;
  const int lq = lane >> 4, lm = lane & 15;
  /* XCD swizzle: 384 blocks = 8 x 48; each XCD gets 16 full M-rows */
  const int lin = blockIdx.y*3 + blockIdx.x;
  const int nl  = (lin & 7)*48 + (lin >> 3);
  const int m0 = (nl / 3) * 64, n0 = (nl % 3) * 128;
  const int wm = (wave >> 1) * 32, wn = (wave & 1) * 64;
  f32x4_t acc[2][4];
  #pragma unroll
  for (int i=0;i<2;i++)
    #pragma unroll
    for (int j=0;j<4;j++)
      acc[i][j] = (f32x4_t){0.f,0.f,0.f,0.f};

  for (int k0 = 0; k0 < K; k0 += 32){
    if (k0) __syncthreads();
    #pragma unroll
    for (int q=0;q<3;q++){
      int o = q*4096 + tid*16;             /* bytes: [0,4096)=As 64x32, [4096,12288)=Bs 128x32 */
      const unsigned short* g;
      if (o < 4096){
        g = A + (size_t)(m0 + (o>>6))*K + k0 + ((o&63)>>1);
      } else {
        int ob = o - 4096;
        g = Bt + (size_t)(n0 + (ob>>6))*K + k0 + ((ob&63)>>1);
      }
      __builtin_amdgcn_global_load_lds(
          (const __attribute__((address_space(1))) void*)g,
          (__attribute__((address_space(3))) void*)((char*)smem + o), 16, 0, 0);
    }
    __syncthreads();
    bf16x8_t af[2], bfv[4];
    #pragma unroll
    for (int i=0;i<2;i++)
      af[i]  = *(const bf16x8_t*)(smem + (wm + i*16 + lm)*32 + lq*8);
    #pragma unroll
    for (int j=0;j<4;j++)
      bfv[j] = *(const bf16x8_t*)(smem + 2048 + (wn + j*16 + lm)*32 + lq*8);
    #pragma unroll
    for (int i=0;i<2;i++)
      #pragma unroll
      for (int j=0;j<4;j++)
        acc[i][j] = __builtin_amdgcn_mfma_f32_16x16x32_bf16(af[i], bfv[j], acc[i][j], 0, 0, 0);
  }

  __syncthreads();
  float* smf = (float*)smem;   /* 64 x 132 fp32 = 33792 B */
  #pragma unroll
  for (int i=0;i<2;i++){
    int rl = wm + i*16 + lq*4;
    #pragma unroll
    for (int j=0;j<4;j++){
      int cl = wn + j*16 + lm;
      #pragma unroll
      for (int r=0;r<4;r++)
        smf[(rl+r)*132 + cl] = acc[i][j][r];
    }
  }
  __syncthreads();
  {
    int row = tid >> 2;
    int cbase = (tid & 3) * 32;
    float* gp = Cf + (size_t)(m0 + row)*ldc + n0 + cbase;
    #pragma unroll
    for (int k=0;k<8;k++){
      float4 v = *(float4*)(gp + k*4);
      float4 a = *(const float4*)&smf[row*132 + cbase + k*4];
      v.x+=a.x; v.y+=a.y; v.z+=a.z; v.w+=a.w;
      *(float4*)(gp + k*4) = v;
    }
  }
}

/* ==== fused conv(k=4)+silu + dt/softplus + cumsum + chunked-SSD matmuls ========
   Conv input now staged into LDS with coalesced 16B loads (was: 35 serial 2B
   strided global loads per thread). Msh aliases the dead stage buffer.        */
__global__ __launch_bounds__(256) void fused_scan_kernel(
    const unsigned short* __restrict__ zxb, const float* __restrict__ dtraw,
    const float* __restrict__ cw, const float* __restrict__ cb,
    const float* __restrict__ dt_bias, const float* __restrict__ A_log,
    const float* __restrict__ D_skip,
    float* __restrict__ cumb, float* __restrict__ Dc,
    unsigned short* __restrict__ Cb, unsigned short* __restrict__ Sb,
    unsigned short* __restrict__ y){
  __shared__ __align__(16) unsigned short Ssh[35*320];   /* stage [row][col]; Msh alias */
  __shared__ __align__(16) unsigned short XshT[192*40];  /* X^T[p_local][t] */
  __shared__ __align__(16) unsigned short BshT[64*40];   /* B^T[n][t] */
  __shared__ __align__(16) unsigned short Bsh[32*72];    /* B[t][n] */
  __shared__ __align__(16) unsigned short Csh[32*72];    /* C[t][n] */
  __shared__ float dtsh[64], Lsh[64], wsh[64];
  unsigned short* Msh = Ssh;                             /* 2*32*40 ushorts, post-conv */
  const int tid = threadIdx.x;
  const int bid = blockIdx.x;
  const int hp = bid & 3, c = (bid >> 2) & 31, b = bid >> 7;
  const int h_base = hp*2;
  const int t0 = c*CHUNK;

  /* ---- dt + raw log-decay for this block's 2 heads ---- */
  if (tid < 64){
    int hi = tid >> 5, t = tid & 31;
    int hg = h_base + hi;
    float raw = dtraw[(size_t)(b*SEQ + t0 + t)*8 + hg];
    float dtv_ = softplus_f(raw + dt_bias[hg]);
    dtsh[tid] = dtv_;
    Lsh[tid]  = dtv_ * (-expf(A_log[hg]));
  }

  /* ---- stage conv input: 35 rows x (X 192 cols | B/C 128 cols), 16B loads ---- */
  {
    const size_t rowbase = (size_t)b*SEQ*ZXB_LD;
    const int gX0 = D_INNER + h_base*96;
    for (int i = tid; i < 35*40; i += 256){
      int row = i/40, seg = i%40;
      int l = t0 - 3 + row;
      bf16x8_t v = {0,0,0,0,0,0,0,0};
      if (l >= 0){
        int col = (seg < 24) ? (gX0 + seg*8) : (1536 + (seg-24)*8);
        v = *(const bf16x8_t*)(zxb + rowbase + (size_t)l*ZXB_LD + col);
      }
      *(bf16x8_t*)&Ssh[row*320 + seg*8] = v;
    }
  }
  __syncthreads();

  /* ---- conv: thread-per-column, rolling 4-tap window from LDS, silu -> LDS ---- */
  #pragma unroll
  for (int it=0; it<2; it++){
    int ci = it*256 + tid;
    if (ci < 320){
      int cch = (ci < 192) ? (h_base*96 + ci) : (D_INNER - 192 + ci);  /* conv channel */
      float4 w4 = *(const float4*)(cw + cch*4);
      float bias = cb[cch];
      float v0=0.f,v1=0.f,v2=0.f,v3=0.f;
      unsigned prev = 0;
      for (int t=-3; t<32; t++){
        float nv = bits_to_f(Ssh[(t+3)*320 + ci]);
        v0=v1; v1=v2; v2=v3; v3=nv;
        if (t < 0) continue;
        float a = silu_f(bias + w4.x*v0 + w4.y*v1 + w4.z*v2 + w4.w*v3);
        unsigned short ub = f_to_bits(a);
        if (ci < 192){
          if (t & 1) *(unsigned*)&XshT[ci*40 + (t-1)] = prev | ((unsigned)ub<<16);
          else prev = ub;
        } else if (cch < CONV_DIM - D_STATE){      /* B: cch 768..831 */
          int n = cch - D_INNER;
          Bsh[t*72 + n] = ub;
          if (t & 1) *(unsigned*)&BshT[n*40 + (t-1)] = prev | ((unsigned)ub<<16);
          else prev = ub;
        } else {                                    /* C: cch 832..895 */
          Csh[t*72 + (cch - D_INNER - D_STATE)] = ub;
        }
      }
    }
  }
  __syncthreads();

  /* ---- sequential cumsum of log-decay; chunk decay products; w-scale ---- */
  if (tid < 2){
    int hg = h_base + tid;
    float L = 0.f;
    float* cbp = cumb + ((size_t)((b*NC + c)*NHEADS) + hg)*CHUNK;
    for (int t=0;t<32;t++){
      L += Lsh[tid*32+t];
      Lsh[tid*32+t] = L;
      cbp[t] = __expf(L);
    }
    Dc[(b*NHEADS + hg)*NC + c] = __expf(L);
    for (int t=0;t<32;t++)
      wsh[tid*32+t] = __expf(L - Lsh[tid*32+t]) * dtsh[tid*32+t];
  }
  __syncthreads();

  const int wave = tid >> 6, lane = tid & 63;
  const int lq = lane >> 4, lm = lane & 15;
  const f32x4_t zero = (f32x4_t){0.f,0.f,0.f,0.f};

  /* ---- waves 0,1: G = C.B^T then M~ (D-skip on diagonal); waves 2,3: Cb out ---- */
  if (wave < 2){
    f32x4_t G[2][2];
    #pragma unroll
    for (int i=0;i<2;i++){ G[i][0]=zero; G[i][1]=zero; }
    #pragma unroll
    for (int kt=0; kt<2; kt++){
      bf16x8_t ca[2], bb[2];
      #pragma unroll
      for (int ti=0;ti<2;ti++)
        ca[ti] = *(const bf16x8_t*)&Csh[(lm+ti*16)*72 + kt*32 + lq*8];
      #pragma unroll
      for (int si=0;si<2;si++)
        bb[si] = *(const bf16x8_t*)&Bsh[(lm+si*16)*72 + kt*32 + lq*8];
      #pragma unroll
      for (int ti=0;ti<2;ti++)
        #pragma unroll
        for (int si=0;si<2;si++)
          G[ti][si] = __builtin_amdgcn_mfma_f32_16x16x32_bf16(ca[ti], bb[si], G[ti][si], 0,0,0);
    }
    int hi = wave;
    float Dk = D_skip[h_base + hi];
    float Lss[2], dts[2];
    #pragma unroll
    for (int si=0;si<2;si++){ Lss[si]=Lsh[hi*32+si*16+lm]; dts[si]=dtsh[hi*32+si*16+lm]; }
    #pragma unroll
    for (int ti=0;ti<2;ti++){
      #pragma unroll
      for (int r=0;r<4;r++){
        int t = ti*16 + lq*4 + r;
        float Lt = Lsh[hi*32 + t];
        #pragma unroll
        for (int si=0;si<2;si++){
          int s = si*16 + lm;
          float m = 0.f;
          if (s <= t){
            m = G[ti][si][r]*__expf(Lt - Lss[si])*dts[si];
            if (s == t) m += Dk;
          }
          Msh[hi*1280 + t*40 + s] = f_to_bits(m);
        }
      }
    }
  } else if (hp == 0){
    int lt = tid - 128;
    for (int i = lt; i < 512; i += 128){
      int t = i >> 4, q = i & 15;
      *(ushort4*)(Cb + ((size_t)(b*SEQ) + t0 + t)*D_STATE + q*4) =
          *(const ushort4*)&Csh[t*72 + q*4];
    }
  }
  __syncthreads();

  /* ---- compute: wave -> (head hi = wave&1, pt-half = wave>>1) ---- */
  {
    int hi = wave & 1, hg = h_base + hi;
    int ptb = (wave >> 1)*3;
    bf16x8_t mf[2];
    #pragma unroll
    for (int tt=0;tt<2;tt++)
      mf[tt] = *(const bf16x8_t*)&Msh[hi*1280 + (lm+tt*16)*40 + lq*8];
    float wv[8];
    #pragma unroll
    for (int j=0;j<8;j++) wv[j] = wsh[hi*32 + lq*8 + j];
    bf16x8_t bw[4];
    #pragma unroll
    for (int nt=0;nt<4;nt++){
      bf16x8_t raw = *(const bf16x8_t*)&BshT[(lm+nt*16)*40 + lq*8];
      #pragma unroll
      for (int j=0;j<8;j++)
        bw[nt][j] = (short)f_to_bits(bits_to_f((unsigned short)raw[j]) * wv[j]);
    }
    const size_t sbase = ((size_t)((b*NC + c)*NHEADS) + hg)*HEADDIM*D_STATE;
    #pragma unroll
    for (int pp=0; pp<3; pp++){
      int pt = ptb + pp;
      bf16x8_t xf = *(const bf16x8_t*)&XshT[(hi*96 + pt*16 + lm)*40 + lq*8];
      /* Y1 (+ D*x via diagonal) */
      #pragma unroll
      for (int tt=0;tt<2;tt++){
        f32x4_t a = __builtin_amdgcn_mfma_f32_16x16x32_bf16(mf[tt], xf, zero, 0,0,0);
        #pragma unroll
        for (int r=0;r<4;r++){
          int t = tt*16 + lq*4 + r;
          y[((size_t)(b*SEQ) + t0 + t)*D_INNER + hg*HEADDIM + pt*16 + lm] = f_to_bits(a[r]);
        }
      }
      /* S = X^T @ (w.B) */
      #pragma unroll
      for (int nt=0;nt<4;nt++){
        f32x4_t s = __builtin_amdgcn_mfma_f32_16x16x32_bf16(xf, bw[nt], zero, 0,0,0);
        #pragma unroll
        for (int r=0;r<4;r++){
          int p = pt*16 + lq*4 + r;
          Sb[sbase + (size_t)p*D_STATE + nt*16 + lm] = f_to_bits(s[r]);
        }
      }
    }
  }
}

/* ---- sequential chunk combine on bf16 S (in-place -> Hin), 4-deep prefetch ---- */
__global__ __launch_bounds__(256) void combine_kernel(
    unsigned short* __restrict__ S, const float* __restrict__ Dc){
  int g = blockIdx.x*256 + threadIdx.x;     /* (b,h,p,nq): 8*8*96*16 = 98304 */
  int nq = g & 15;
  int p  = (g >> 4) % 96;
  int h  = (g / (16*96)) & 7;
  int b  = g / (16*96*8);
  const float* Dp = Dc + (size_t)(b*NHEADS + h)*NC;
  const size_t cstride = (size_t)NHEADS*HEADDIM*D_STATE;   /* 49152 */
  size_t base = (((size_t)(b*NC)*NHEADS + h)*HEADDIM + p)*D_STATE + nq*4;
  float H0=0.f,H1=0.f,H2=0.f,H3=0.f;
  #pragma unroll 1
  for (int c=0;c<NC;c+=4){
    ushort4 s0 = *(ushort4*)(S + base);
    ushort4 s1 = *(ushort4*)(S + base +   cstride);
    ushort4 s2 = *(ushort4*)(S + base + 2*cstride);
    ushort4 s3 = *(ushort4*)(S + base + 3*cstride);
    float D;
#define CSTEP(sv, cc) \
    *(ushort4*)(S + base) = make_ushort4(f_to_bits(H0),f_to_bits(H1),f_to_bits(H2),f_to_bits(H3)); \
    D = Dp[cc]; \
    H0 = fmaf(D,H0,bits_to_f(sv.x)); H1 = fmaf(D,H1,bits_to_f(sv.y)); \
    H2 = fmaf(D,H2,bits_to_f(sv.z)); H3 = fmaf(D,H3,bits_to_f(sv.w)); \
    base += cstride;
    CSTEP(s0, c) CSTEP(s1, c+1) CSTEP(s2, c+2) CSTEP(s3, c+3)
#undef CSTEP
  }
}

/* ==== fused: y_final = y + cum*(C@Hin^T); gate with silu(z); RMSNorm -> ygb ====
   512 threads: one wave per head (8 waves/CU for latency hiding of 2B gathers) */
__global__ __launch_bounds__(512) void hinfuse_kernel(
    const unsigned short* __restrict__ Cb, const unsigned short* __restrict__ Hinb,
    const float* __restrict__ cumb, const unsigned short* __restrict__ zxb,
    const float* __restrict__ nw, const unsigned short* __restrict__ ybuf,
    unsigned short* __restrict__ ygb){
  __shared__ __align__(16) unsigned short Vsh[32*VP];
  __shared__ float cumsh[256];
  __shared__ float rowsq[32];
  const int tid = threadIdx.x;
  const int c = blockIdx.x & 31, b = blockIdx.x >> 5;
  const int t0 = c*CHUNK;
  if (tid < 256)
    cumsh[tid] = cumb[(size_t)((b*NC + c)*NHEADS)*CHUNK + tid];   /* h=tid>>5,t=tid&31 */
  if (tid < 32) rowsq[tid] = 0.f;
  __syncthreads();
  const int wave = tid >> 6, lane = tid & 63;
  const int lq = lane >> 4, lm = lane & 15;
  const f32x4_t zero = (f32x4_t){0.f,0.f,0.f,0.f};
  float sql[2][4] = {};
  const int h = wave;
  const unsigned short* Hb = Hinb + ((size_t)((b*NC + c)*NHEADS) + h)*HEADDIM*D_STATE;
  bf16x8_t ca[2][2];
  #pragma unroll
  for (int tt=0;tt<2;tt++)
    #pragma unroll
    for (int kt=0;kt<2;kt++)
      ca[tt][kt] = *(const bf16x8_t*)(Cb +
          ((size_t)(b*SEQ) + t0 + tt*16 + lm)*D_STATE + kt*32 + lq*8);
  #pragma unroll
  for (int pt=0; pt<6; pt++){
    bf16x8_t hf0 = *(const bf16x8_t*)&Hb[(size_t)(lm+pt*16)*D_STATE + lq*8];
    bf16x8_t hf1 = *(const bf16x8_t*)&Hb[(size_t)(lm+pt*16)*D_STATE + 32 + lq*8];
    f32x4_t acc[2];
    #pragma unroll
    for (int tt=0;tt<2;tt++){
      acc[tt] = __builtin_amdgcn_mfma_f32_16x16x32_bf16(ca[tt][0], hf0, zero, 0,0,0);
      acc[tt] = __builtin_amdgcn_mfma_f32_16x16x32_bf16(ca[tt][1], hf1, acc[tt], 0,0,0);
    }
    int pcol = h*HEADDIM + pt*16 + lm;
    #pragma unroll
    for (int tt=0;tt<2;tt++){
      #pragma unroll
      for (int r=0;r<4;r++){
        int t = tt*16 + lq*4 + r;
        size_t row = (size_t)(b*SEQ) + t0 + t;
        float yv = bits_to_f(ybuf[row*D_INNER + pcol]) + cumsh[h*32+t]*acc[tt][r];
        float z  = bits_to_f(zxb[row*ZXB_LD + pcol]);
        float v  = yv * silu_f(z);
        Vsh[t*VP + pcol] = f_to_bits(v);
        sql[tt][r] += v*v;
      }
    }
  }
  /* reduce v^2 over the 16 lm lanes, then one LDS atomic per (t) per wave */
  #pragma unroll
  for (int tt=0;tt<2;tt++)
    #pragma unroll
    for (int r=0;r<4;r++){
      float v = sql[tt][r];
      v += __shfl_xor(v,1); v += __shfl_xor(v,2);
      v += __shfl_xor(v,4); v += __shfl_xor(v,8);
      if (lm == 0) atomicAdd(&rowsq[tt*16 + lq*4 + r], v);
    }
  __syncthreads();
  if (tid < 32) rowsq[tid] = rsqrtf(rowsq[tid]*(1.f/D_INNER) + 1e-5f);
  __syncthreads();
  for (int i=tid; i<32*192; i+=512){
    int t = i/192, q = i%192;
    ushort4 pv = *(const ushort4*)&Vsh[t*VP + q*4];
    float rms = rowsq[t];
    float4 w4 = *(const float4*)(nw + q*4);
    ushort4 o;
    o.x = f_to_bits(bits_to_f(pv.x)*rms*w4.x);
    o.y = f_to_bits(bits_to_f(pv.y)*rms*w4.y);
    o.z = f_to_bits(bits_to_f(pv.z)*rms*w4.z);
    o.w = f_to_bits(bits_to_f(pv.w)*rms*w4.w);
    *(ushort4*)(ygb + ((size_t)(b*SEQ) + t0 + t)*D_INNER + q*4) = o;
  }
}

extern "C" void kernel_launch(void* const* d_in, const int* in_sizes, int n_in,
                              void* d_out, int out_size, void* d_ws, size_t ws_size,
                              hipStream_t stream){
  const float* x0      = (const float*)d_in[0];
  const float* ln_w    = (const float*)d_in[1];
  const float* ln_b    = (const float*)d_in[2];
  const float* W_in    = (const float*)d_in[3];
  const float* conv_w  = (const float*)d_in[4];
  const float* conv_b  = (const float*)d_in[5];
  const float* dt_bias = (const float*)d_in[6];
  const float* A_log   = (const float*)d_in[7];
  const float* D_skip  = (const float*)d_in[8];
  const float* norm_w  = (const float*)d_in[9];
  const float* W_out   = (const float*)d_in[10];
  float* out = (float*)d_out;

  /* workspace (float units), ~91 MB */
  float* p    = (float*)d_ws;
  unsigned short* zxb = (unsigned short*)p;   p += (size_t)ROWS*ZXB_LD/2;
  float* dtraw = p;  p += (size_t)ROWS*8;
  float* cumb  = p;  p += (size_t)BATCH*NHEADS*SEQ;
  float* Dc    = p;  p += (size_t)BATCH*NHEADS*NC;
  unsigned short* ybuf = (unsigned short*)p;  p += (size_t)ROWS*D_INNER/2;
  unsigned short* ygb  = (unsigned short*)p;  p += (size_t)ROWS*D_INNER/2;
  unsigned short* Sb   = (unsigned short*)p;  p += (size_t)BATCH*NC*NHEADS*HEADDIM*D_STATE/2;
  unsigned short* Cb   = (unsigned short*)p;  p += (size_t)ROWS*D_STATE/2;
  bf16* Wt  = (bf16*)p; p += (size_t)NUM_LAYERS*NPAD_IN*D_MODEL/2;
  bf16* Wot = (bf16*)p;
  bf16* hnb = (bf16*)Sb;   /* alias: live ln -> gemm_in, dead before fused_scan */

  hipMemcpyAsync(out, x0, (size_t)ROWS*D_MODEL*sizeof(float),
                 hipMemcpyDeviceToDevice, stream);

  wconv_kernel<<<dim3(NPAD_IN/32, D_MODEL/32, NUM_LAYERS), dim3(32,8), 0, stream>>>(
      W_in, Wt, D_MODEL, D_IN_PROJ, NPAD_IN);
  wconv_kernel<<<dim3(NPAD_OUT/32, D_INNER/32, NUM_LAYERS), dim3(32,8), 0, stream>>>(
      W_out, Wot, D_INNER, D_MODEL, NPAD_OUT);

  for (int i=0;i<NUM_LAYERS;i++){
    ln_kernel<<<ROWS/4,256,0,stream>>>(out, ln_w+(size_t)i*D_MODEL, ln_b+(size_t)i*D_MODEL, hnb);
    gemm_in<<<dim3(NPAD_IN/128, ROWS/128), 256, 0, stream>>>(
        (const unsigned short*)hnb, (const unsigned short*)(Wt + (size_t)i*NPAD_IN*D_MODEL),
        zxb, dtraw, D_MODEL);
    fused_scan_kernel<<<BATCH*NC*4, 256, 0, stream>>>(
        zxb, dtraw, conv_w + (size_t)i*CONV_DIM*4, conv_b + (size_t)i*CONV_DIM,
        dt_bias+(size_t)i*NHEADS, A_log+(size_t)i*NHEADS, D_skip+(size_t)i*NHEADS,
        cumb, Dc, Cb, Sb, ybuf);
    combine_kernel<<<(BATCH*NHEADS*HEADDIM*16)/256, 256, 0, stream>>>(Sb, Dc);
    hinfuse_kernel<<<BATCH*NC, 512, 0, stream>>>(
        Cb, Sb, cumb, zxb, norm_w+(size_t)i*D_INNER, ybuf, ygb);
    gemm_out<<<dim3(NPAD_OUT/128, ROWS/64), 256, 0, stream>>>(
        (const unsigned short*)ygb, (const unsigned short*)(Wot + (size_t)i*NPAD_OUT*D_INNER),
        out, D_INNER, D_MODEL);
  }
}

// Round 3
// 767.501 us; speedup vs baseline: 1.0151x; 1.0151x over previous
//
#include <hip/hip_runtime.h>
#include <hip/hip_bf16.h>
#include <math.h>

#define D_MODEL 384
#define D_STATE 64
#define D_INNER 768
#define HEADDIM 96
#define NHEADS 8
#define CONV_DIM 896
#define D_IN_PROJ 1672
#define ZXB_LD 1664        /* bf16 zx row stride (z,X,B,C); dt split to fp32 */
#define BATCH 8
#define SEQ 1024
#define ROWS (BATCH*SEQ)   /* 8192 */
#define NUM_LAYERS 6
#define NC 32              /* chunks */
#define CHUNK 32           /* timesteps per chunk */
#define NPAD_IN 1792       /* 14 * 128 */
#define NPAD_OUT 384       /* 3 * 128  */
#define VP 776             /* padded Vsh row (shorts); 4(lm+lq) bank spread is even */

typedef __hip_bfloat16 bf16;
using bf16x8_t = __attribute__((ext_vector_type(8))) short;
using f32x4_t  = __attribute__((ext_vector_type(4))) float;

__device__ __forceinline__ float softplus_f(float v){
  return v > 20.f ? v : log1pf(expf(v));
}
__device__ __forceinline__ float silu_f(float v){
  return v / (1.f + expf(-v));
}
__device__ __forceinline__ float bits_to_f(unsigned short u){
  union{unsigned u32; float f;} cv; cv.u32 = ((unsigned)u)<<16; return cv.f;
}
__device__ __forceinline__ unsigned short f_to_bits(float f){
  union{bf16 b; unsigned short u;} cv; cv.b = __float2bfloat16(f); return cv.u;
}

/* ------- weight transpose + fp32->bf16, all layers batched via grid.z ---------- */
__global__ void wconv_kernel(const float* __restrict__ W, bf16* __restrict__ Wt,
                             int K, int N, int Npad){
  __shared__ float tile[32][33];
  W  += (size_t)blockIdx.z*K*N;
  Wt += (size_t)blockIdx.z*Npad*K;
  int kb = blockIdx.y*32, nb = blockIdx.x*32;
  int tx = threadIdx.x, ty = threadIdx.y;   /* 32 x 8 */
  #pragma unroll
  for (int r=0;r<32;r+=8){
    int k = kb+ty+r, n = nb+tx;
    tile[ty+r][tx] = (k<K && n<N) ? W[(size_t)k*N+n] : 0.f;
  }
  __syncthreads();
  #pragma unroll
  for (int r=0;r<32;r+=8){
    int n = nb+ty+r, k = kb+tx;
    if (n<Npad && k<K) Wt[(size_t)n*K+k] = __float2bfloat16(tile[tx][ty+r]);
  }
}

/* ---------------- LayerNorm (layer 0 only): one WAVE per row of 384 -> bf16 ---- */
__global__ __launch_bounds__(256) void ln_kernel(const float* __restrict__ x, const float* __restrict__ w,
                          const float* __restrict__ b, unsigned short* __restrict__ o){
  const int wave = threadIdx.x >> 6, lane = threadIdx.x & 63;
  const int r = blockIdx.x*4 + wave;
  const float* xr = x + (size_t)r*D_MODEL;
  float2 v[3];
  float s = 0.f, sq = 0.f;
  #pragma unroll
  for (int e=0;e<3;e++){
    v[e] = *(const float2*)(xr + e*128 + lane*2);
    s  += v[e].x + v[e].y;
    sq += v[e].x*v[e].x + v[e].y*v[e].y;
  }
  #pragma unroll
  for (int off=1; off<64; off<<=1){
    s  += __shfl_xor(s, off);
    sq += __shfl_xor(sq, off);
  }
  float mu  = s*(1.f/D_MODEL);
  float var = sq*(1.f/D_MODEL) - mu*mu;
  var = var < 0.f ? 0.f : var;
  float rstd = rsqrtf(var + 1e-12f);
  unsigned short* orow = o + (size_t)r*D_MODEL;
  #pragma unroll
  for (int e=0;e<3;e++){
    int c = e*128 + lane*2;
    float2 wv = *(const float2*)(w + c);
    float2 bv = *(const float2*)(b + c);
    ushort2 ov;
    ov.x = f_to_bits((v[e].x-mu)*rstd*wv.x + bv.x);
    ov.y = f_to_bits((v[e].y-mu)*rstd*wv.y + bv.y);
    *(ushort2*)(orow + c) = ov;
  }
}

/* ------- bf16 MFMA GEMM (in-proj): bf16 zxb out + fp32 dtraw --------------------
   128x128 tile; XCD-swizzled so same-M blocks share an XCD L2 (A fetched once). */
__global__ __launch_bounds__(256) void gemm_in(
    const unsigned short* __restrict__ A,   /* M x K bf16, row-major */
    const unsigned short* __restrict__ Bt,  /* Npad x K bf16 (B transposed) */
    unsigned short* __restrict__ Cbf,       /* M x ZXB_LD bf16 */
    float* __restrict__ dtraw,              /* M x 8 fp32 */
    int K){
  __shared__ __align__(16) unsigned short smem[128*136];  /* 34 KB */
  unsigned short* As = smem;          /* 128*32 */
  unsigned short* Bs = smem + 4096;   /* 128*32 */
  const int tid = threadIdx.x;
  const int wave = tid >> 6, lane = tid & 63;
  const int lq = lane >> 4, lm = lane & 15;
  /* XCD swizzle: 896 blocks = 8 XCDs x 112; each XCD gets 8 full M-rows */
  const int lin = blockIdx.y*14 + blockIdx.x;
  const int nl  = (lin & 7)*112 + (lin >> 3);
  const int m0 = (nl / 14) * 128, n0 = (nl % 14) * 128;
  const int wm = (wave >> 1) * 64, wn = (wave & 1) * 64;
  f32x4_t acc[4][4];
  #pragma unroll
  for (int i=0;i<4;i++)
    #pragma unroll
    for (int j=0;j<4;j++)
      acc[i][j] = (f32x4_t){0.f,0.f,0.f,0.f};

  for (int k0 = 0; k0 < K; k0 += 32){
    if (k0) __syncthreads();
    #pragma unroll
    for (int q=0;q<2;q++){
      int o = q*4096 + wave*1024 + lane*16;
      int m = o >> 6;
      int kb = o & 63;
      const unsigned short* ga = A  + (size_t)(m0+m)*K + k0 + (kb>>1);
      __builtin_amdgcn_global_load_lds(
          (const __attribute__((address_space(1))) void*)ga,
          (__attribute__((address_space(3))) void*)((char*)As + o), 16, 0, 0);
      const unsigned short* gb = Bt + (size_t)(n0+m)*K + k0 + (kb>>1);
      __builtin_amdgcn_global_load_lds(
          (const __attribute__((address_space(1))) void*)gb,
          (__attribute__((address_space(3))) void*)((char*)Bs + o), 16, 0, 0);
    }
    __syncthreads();
    bf16x8_t af[4], bfv[4];
    #pragma unroll
    for (int i=0;i<4;i++)
      af[i]  = *(const bf16x8_t*)(As + (wm + i*16 + lm)*32 + lq*8);
    #pragma unroll
    for (int j=0;j<4;j++)
      bfv[j] = *(const bf16x8_t*)(Bs + (wn + j*16 + lm)*32 + lq*8);
    #pragma unroll
    for (int i=0;i<4;i++)
      #pragma unroll
      for (int j=0;j<4;j++)
        acc[i][j] = __builtin_amdgcn_mfma_f32_16x16x32_bf16(af[i], bfv[j], acc[i][j], 0, 0, 0);
  }

  if (n0 == ZXB_LD){
    /* dt block: local cols 0..7 are dt (fp32 direct); rest is padding */
    if ((wave & 1) == 0 && lm < 8){
      #pragma unroll
      for (int i=0;i<4;i++){
        int row = m0 + wm + i*16 + lq*4;
        #pragma unroll
        for (int r=0;r<4;r++)
          dtraw[(size_t)(row+r)*8 + lm] = acc[i][0][r];
      }
    }
    return;
  }
  __syncthreads();   /* done reading As/Bs: reuse smem as C-stage */
  #pragma unroll
  for (int i=0;i<4;i++){
    int rl = wm + i*16 + lq*4;
    #pragma unroll
    for (int j=0;j<4;j++){
      int cl = wn + j*16 + lm;
      #pragma unroll
      for (int r=0;r<4;r++)
        smem[(rl+r)*136 + cl] = f_to_bits(acc[i][j][r]);
    }
  }
  __syncthreads();
  /* 2 threads/row, 8x 16B stores each */
  {
    int row = tid >> 1;
    int cbase = (tid & 1) * 64;
    size_t gb = (size_t)(m0 + row) * ZXB_LD + n0 + cbase;
    #pragma unroll
    for (int k=0;k<8;k++)
      *(bf16x8_t*)(Cbf + gb + k*8) = *(const bf16x8_t*)&smem[row*136 + cbase + k*8];
  }
}

/* ==== fused conv(k=4)+silu + dt/softplus + cumsum + chunked-SSD matmuls ======== */
__global__ __launch_bounds__(256) void fused_scan_kernel(
    const unsigned short* __restrict__ zxb, const float* __restrict__ dtraw,
    const float* __restrict__ cw, const float* __restrict__ cb,
    const float* __restrict__ dt_bias, const float* __restrict__ A_log,
    const float* __restrict__ D_skip,
    float* __restrict__ cumb, float* __restrict__ Dc,
    unsigned short* __restrict__ Cb, unsigned short* __restrict__ Sb,
    unsigned short* __restrict__ y){
  __shared__ __align__(16) unsigned short Ssh[35*320];   /* stage [row][col]; Msh alias */
  __shared__ __align__(16) unsigned short XshT[192*40];  /* X^T[p_local][t] */
  __shared__ __align__(16) unsigned short BshT[64*40];   /* B^T[n][t] */
  __shared__ __align__(16) unsigned short Bsh[32*72];    /* B[t][n] */
  __shared__ __align__(16) unsigned short Csh[32*72];    /* C[t][n] */
  __shared__ float dtsh[64], Lsh[64], wsh[64];
  unsigned short* Msh = Ssh;                             /* 2*32*40 ushorts, post-conv */
  const int tid = threadIdx.x;
  const int bid = blockIdx.x;
  const int hp = bid & 3, c = (bid >> 2) & 31, b = bid >> 7;
  const int h_base = hp*2;
  const int t0 = c*CHUNK;

  /* ---- dt + raw log-decay for this block's 2 heads ---- */
  if (tid < 64){
    int hi = tid >> 5, t = tid & 31;
    int hg = h_base + hi;
    float raw = dtraw[(size_t)(b*SEQ + t0 + t)*8 + hg];
    float dtv_ = softplus_f(raw + dt_bias[hg]);
    dtsh[tid] = dtv_;
    Lsh[tid]  = dtv_ * (-expf(A_log[hg]));
  }

  /* ---- stage conv input: 35 rows x (X 192 cols | B/C 128 cols), 16B loads ---- */
  {
    const size_t rowbase = (size_t)b*SEQ*ZXB_LD;
    const int gX0 = D_INNER + h_base*96;
    for (int i = tid; i < 35*40; i += 256){
      int row = i/40, seg = i%40;
      int l = t0 - 3 + row;
      bf16x8_t v = {0,0,0,0,0,0,0,0};
      if (l >= 0){
        int col = (seg < 24) ? (gX0 + seg*8) : (1536 + (seg-24)*8);
        v = *(const bf16x8_t*)(zxb + rowbase + (size_t)l*ZXB_LD + col);
      }
      *(bf16x8_t*)&Ssh[row*320 + seg*8] = v;
    }
  }
  __syncthreads();

  /* ---- conv: thread-per-column, rolling 4-tap window from LDS, silu -> LDS ---- */
  #pragma unroll
  for (int it=0; it<2; it++){
    int ci = it*256 + tid;
    if (ci < 320){
      int cch = (ci < 192) ? (h_base*96 + ci) : (D_INNER - 192 + ci);  /* conv channel */
      float4 w4 = *(const float4*)(cw + cch*4);
      float bias = cb[cch];
      float v0=0.f,v1=0.f,v2=0.f,v3=0.f;
      unsigned prev = 0;
      for (int t=-3; t<32; t++){
        float nv = bits_to_f(Ssh[(t+3)*320 + ci]);
        v0=v1; v1=v2; v2=v3; v3=nv;
        if (t < 0) continue;
        float a = silu_f(bias + w4.x*v0 + w4.y*v1 + w4.z*v2 + w4.w*v3);
        unsigned short ub = f_to_bits(a);
        if (ci < 192){
          if (t & 1) *(unsigned*)&XshT[ci*40 + (t-1)] = prev | ((unsigned)ub<<16);
          else prev = ub;
        } else if (cch < CONV_DIM - D_STATE){      /* B: cch 768..831 */
          int n = cch - D_INNER;
          Bsh[t*72 + n] = ub;
          if (t & 1) *(unsigned*)&BshT[n*40 + (t-1)] = prev | ((unsigned)ub<<16);
          else prev = ub;
        } else {                                    /* C: cch 832..895 */
          Csh[t*72 + (cch - D_INNER - D_STATE)] = ub;
        }
      }
    }
  }
  __syncthreads();

  /* ---- sequential cumsum of log-decay; chunk decay products; w-scale ---- */
  if (tid < 2){
    int hg = h_base + tid;
    float L = 0.f;
    float* cbp = cumb + ((size_t)((b*NC + c)*NHEADS) + hg)*CHUNK;
    for (int t=0;t<32;t++){
      L += Lsh[tid*32+t];
      Lsh[tid*32+t] = L;
      cbp[t] = __expf(L);
    }
    Dc[(b*NHEADS + hg)*NC + c] = __expf(L);
    for (int t=0;t<32;t++)
      wsh[tid*32+t] = __expf(L - Lsh[tid*32+t]) * dtsh[tid*32+t];
  }
  __syncthreads();

  const int wave = tid >> 6, lane = tid & 63;
  const int lq = lane >> 4, lm = lane & 15;
  const f32x4_t zero = (f32x4_t){0.f,0.f,0.f,0.f};

  /* ---- waves 0,1: G = C.B^T then M~ (D-skip on diagonal); waves 2,3: Cb out ---- */
  if (wave < 2){
    f32x4_t G[2][2];
    #pragma unroll
    for (int i=0;i<2;i++){ G[i][0]=zero; G[i][1]=zero; }
    #pragma unroll
    for (int kt=0; kt<2; kt++){
      bf16x8_t ca[2], bb[2];
      #pragma unroll
      for (int ti=0;ti<2;ti++)
        ca[ti] = *(const bf16x8_t*)&Csh[(lm+ti*16)*72 + kt*32 + lq*8];
      #pragma unroll
      for (int si=0;si<2;si++)
        bb[si] = *(const bf16x8_t*)&Bsh[(lm+si*16)*72 + kt*32 + lq*8];
      #pragma unroll
      for (int ti=0;ti<2;ti++)
        #pragma unroll
        for (int si=0;si<2;si++)
          G[ti][si] = __builtin_amdgcn_mfma_f32_16x16x32_bf16(ca[ti], bb[si], G[ti][si], 0,0,0);
    }
    int hi = wave;
    float Dk = D_skip[h_base + hi];
    float Lss[2], dts[2];
    #pragma unroll
    for (int si=0;si<2;si++){ Lss[si]=Lsh[hi*32+si*16+lm]; dts[si]=dtsh[hi*32+si*16+lm]; }
    #pragma unroll
    for (int ti=0;ti<2;ti++){
      #pragma unroll
      for (int r=0;r<4;r++){
        int t = ti*16 + lq*4 + r;
        float Lt = Lsh[hi*32 + t];
        #pragma unroll
        for (int si=0;si<2;si++){
          int s = si*16 + lm;
          float m = 0.f;
          if (s <= t){
            m = G[ti][si][r]*__expf(Lt - Lss[si])*dts[si];
            if (s == t) m += Dk;
          }
          Msh[hi*1280 + t*40 + s] = f_to_bits(m);
        }
      }
    }
  } else if (hp == 0){
    int lt = tid - 128;
    for (int i = lt; i < 512; i += 128){
      int t = i >> 4, q = i & 15;
      *(ushort4*)(Cb + ((size_t)(b*SEQ) + t0 + t)*D_STATE + q*4) =
          *(const ushort4*)&Csh[t*72 + q*4];
    }
  }
  __syncthreads();

  /* ---- compute: wave -> (head hi = wave&1, pt-half = wave>>1) ---- */
  {
    int hi = wave & 1, hg = h_base + hi;
    int ptb = (wave >> 1)*3;
    bf16x8_t mf[2];
    #pragma unroll
    for (int tt=0;tt<2;tt++)
      mf[tt] = *(const bf16x8_t*)&Msh[hi*1280 + (lm+tt*16)*40 + lq*8];
    float wv[8];
    #pragma unroll
    for (int j=0;j<8;j++) wv[j] = wsh[hi*32 + lq*8 + j];
    bf16x8_t bw[4];
    #pragma unroll
    for (int nt=0;nt<4;nt++){
      bf16x8_t raw = *(const bf16x8_t*)&BshT[(lm+nt*16)*40 + lq*8];
      #pragma unroll
      for (int j=0;j<8;j++)
        bw[nt][j] = (short)f_to_bits(bits_to_f((unsigned short)raw[j]) * wv[j]);
    }
    const size_t sbase = ((size_t)((b*NC + c)*NHEADS) + hg)*HEADDIM*D_STATE;
    #pragma unroll
    for (int pp=0; pp<3; pp++){
      int pt = ptb + pp;
      bf16x8_t xf = *(const bf16x8_t*)&XshT[(hi*96 + pt*16 + lm)*40 + lq*8];
      /* Y1 (+ D*x via diagonal) */
      #pragma unroll
      for (int tt=0;tt<2;tt++){
        f32x4_t a = __builtin_amdgcn_mfma_f32_16x16x32_bf16(mf[tt], xf, zero, 0,0,0);
        #pragma unroll
        for (int r=0;r<4;r++){
          int t = tt*16 + lq*4 + r;
          y[((size_t)(b*SEQ) + t0 + t)*D_INNER + hg*HEADDIM + pt*16 + lm] = f_to_bits(a[r]);
        }
      }
      /* S = X^T @ (w.B) */
      #pragma unroll
      for (int nt=0;nt<4;nt++){
        f32x4_t s = __builtin_amdgcn_mfma_f32_16x16x32_bf16(xf, bw[nt], zero, 0,0,0);
        #pragma unroll
        for (int r=0;r<4;r++){
          int p = pt*16 + lq*4 + r;
          Sb[sbase + (size_t)p*D_STATE + nt*16 + lm] = f_to_bits(s[r]);
        }
      }
    }
  }
}

/* ---- sequential chunk combine on bf16 S (in-place -> Hin), 4-deep prefetch ---- */
__global__ __launch_bounds__(256) void combine_kernel(
    unsigned short* __restrict__ S, const float* __restrict__ Dc){
  int g = blockIdx.x*256 + threadIdx.x;     /* (b,h,p,nq): 8*8*96*16 = 98304 */
  int nq = g & 15;
  int p  = (g >> 4) % 96;
  int h  = (g / (16*96)) & 7;
  int b  = g / (16*96*8);
  const float* Dp = Dc + (size_t)(b*NHEADS + h)*NC;
  const size_t cstride = (size_t)NHEADS*HEADDIM*D_STATE;   /* 49152 */
  size_t base = (((size_t)(b*NC)*NHEADS + h)*HEADDIM + p)*D_STATE + nq*4;
  float H0=0.f,H1=0.f,H2=0.f,H3=0.f;
  #pragma unroll 1
  for (int c=0;c<NC;c+=4){
    ushort4 s0 = *(ushort4*)(S + base);
    ushort4 s1 = *(ushort4*)(S + base +   cstride);
    ushort4 s2 = *(ushort4*)(S + base + 2*cstride);
    ushort4 s3 = *(ushort4*)(S + base + 3*cstride);
    float D;
#define CSTEP(sv, cc) \
    *(ushort4*)(S + base) = make_ushort4(f_to_bits(H0),f_to_bits(H1),f_to_bits(H2),f_to_bits(H3)); \
    D = Dp[cc]; \
    H0 = fmaf(D,H0,bits_to_f(sv.x)); H1 = fmaf(D,H1,bits_to_f(sv.y)); \
    H2 = fmaf(D,H2,bits_to_f(sv.z)); H3 = fmaf(D,H3,bits_to_f(sv.w)); \
    base += cstride;
    CSTEP(s0, c) CSTEP(s1, c+1) CSTEP(s2, c+2) CSTEP(s3, c+3)
#undef CSTEP
  }
}

/* ==== fused tail: y+cum*(C@Hin^T), silu(z) gate, RMSNorm, @W_out into residual,
   and NEXT layer's LayerNorm -> hnb. Block (b,c) owns complete 32 rows.       ==== */
__global__ __launch_bounds__(512) void hinfuse_out_kernel(
    const unsigned short* __restrict__ Cb, const unsigned short* __restrict__ Hinb,
    const float* __restrict__ cumb, const unsigned short* __restrict__ zxb,
    const float* __restrict__ nw, const unsigned short* __restrict__ ybuf,
    const unsigned short* __restrict__ Wot,   /* NPAD_OUT x D_INNER bf16 */
    float* __restrict__ out,                  /* residual stream fp32, RMW */
    const float* __restrict__ lnw, const float* __restrict__ lnb,
    unsigned short* __restrict__ hnb,         /* next-layer LN out, bf16 */
    int do_ln){
  __shared__ __align__(16) unsigned short Vsh[32*VP];
  __shared__ float cumsh[256];
  __shared__ float rowsq[32];
  __shared__ float rowsum2[32], rowsq2[32], mu_s[32], rs_s[32];
  const int tid = threadIdx.x;
  const int c = blockIdx.x & 31, b = blockIdx.x >> 5;
  const int t0 = c*CHUNK;
  if (tid < 256)
    cumsh[tid] = cumb[(size_t)((b*NC + c)*NHEADS)*CHUNK + tid];   /* h=tid>>5,t=tid&31 */
  if (tid < 32){ rowsq[tid] = 0.f; rowsum2[tid] = 0.f; rowsq2[tid] = 0.f; }
  __syncthreads();
  const int wave = tid >> 6, lane = tid & 63;
  const int lq = lane >> 4, lm = lane & 15;
  const f32x4_t zero = (f32x4_t){0.f,0.f,0.f,0.f};

  /* ---- phase 1: V = (y + cum*C@Hin^T) * silu(z) into Vsh; one wave per head --- */
  {
    float sql[2][4] = {};
    const int h = wave;
    const unsigned short* Hb = Hinb + ((size_t)((b*NC + c)*NHEADS) + h)*HEADDIM*D_STATE;
    bf16x8_t ca[2][2];
    #pragma unroll
    for (int tt=0;tt<2;tt++)
      #pragma unroll
      for (int kt=0;kt<2;kt++)
        ca[tt][kt] = *(const bf16x8_t*)(Cb +
            ((size_t)(b*SEQ) + t0 + tt*16 + lm)*D_STATE + kt*32 + lq*8);
    #pragma unroll
    for (int pt=0; pt<6; pt++){
      bf16x8_t hf0 = *(const bf16x8_t*)&Hb[(size_t)(lm+pt*16)*D_STATE + lq*8];
      bf16x8_t hf1 = *(const bf16x8_t*)&Hb[(size_t)(lm+pt*16)*D_STATE + 32 + lq*8];
      f32x4_t acc[2];
      #pragma unroll
      for (int tt=0;tt<2;tt++){
        acc[tt] = __builtin_amdgcn_mfma_f32_16x16x32_bf16(ca[tt][0], hf0, zero, 0,0,0);
        acc[tt] = __builtin_amdgcn_mfma_f32_16x16x32_bf16(ca[tt][1], hf1, acc[tt], 0,0,0);
      }
      int pcol = h*HEADDIM + pt*16 + lm;
      #pragma unroll
      for (int tt=0;tt<2;tt++){
        #pragma unroll
        for (int r=0;r<4;r++){
          int t = tt*16 + lq*4 + r;
          size_t row = (size_t)(b*SEQ) + t0 + t;
          float yv = bits_to_f(ybuf[row*D_INNER + pcol]) + cumsh[h*32+t]*acc[tt][r];
          float z  = bits_to_f(zxb[row*ZXB_LD + pcol]);
          float v  = yv * silu_f(z);
          Vsh[t*VP + pcol] = f_to_bits(v);
          sql[tt][r] += v*v;
        }
      }
    }
    #pragma unroll
    for (int tt=0;tt<2;tt++)
      #pragma unroll
      for (int r=0;r<4;r++){
        float v = sql[tt][r];
        v += __shfl_xor(v,1); v += __shfl_xor(v,2);
        v += __shfl_xor(v,4); v += __shfl_xor(v,8);
        if (lm == 0) atomicAdd(&rowsq[tt*16 + lq*4 + r], v);
      }
  }
  __syncthreads();
  if (tid < 32) rowsq[tid] = rsqrtf(rowsq[tid]*(1.f/D_INNER) + 1e-5f);
  __syncthreads();
  /* ---- normalize V in place (RMSNorm * norm_w), bf16 -> Vsh ---- */
  for (int i=tid; i<32*192; i+=512){
    int t = i/192, q = i%192;
    ushort4 pv = *(const ushort4*)&Vsh[t*VP + q*4];
    float rms = rowsq[t];
    float4 w4 = *(const float4*)(nw + q*4);
    ushort4 o;
    o.x = f_to_bits(bits_to_f(pv.x)*rms*w4.x);
    o.y = f_to_bits(bits_to_f(pv.y)*rms*w4.y);
    o.z = f_to_bits(bits_to_f(pv.z)*rms*w4.z);
    o.w = f_to_bits(bits_to_f(pv.w)*rms*w4.w);
    *(ushort4*)&Vsh[t*VP + q*4] = o;
  }
  __syncthreads();

  /* ---- phase 2: delta(32x384) = Vsh(32x768) @ Wot^T; each wave 48 cols ---- */
  const int wn = wave*48;
  f32x4_t acc[2][3];
  #pragma unroll
  for (int i=0;i<2;i++)
    #pragma unroll
    for (int j=0;j<3;j++)
      acc[i][j] = zero;
  for (int k0=0; k0<D_INNER; k0+=32){
    bf16x8_t af[2], bfv[3];
    #pragma unroll
    for (int i=0;i<2;i++)
      af[i] = *(const bf16x8_t*)&Vsh[(i*16 + lm)*VP + k0 + lq*8];
    #pragma unroll
    for (int j=0;j<3;j++)
      bfv[j] = *(const bf16x8_t*)(Wot + (size_t)(wn + j*16 + lm)*D_INNER + k0 + lq*8);
    #pragma unroll
    for (int i=0;i<2;i++)
      #pragma unroll
      for (int j=0;j<3;j++)
        acc[i][j] = __builtin_amdgcn_mfma_f32_16x16x32_bf16(af[i], bfv[j], acc[i][j], 0,0,0);
  }

  /* ---- phase 3: residual RMW into out; LN stats; hnb for next layer ---- */
  #pragma unroll
  for (int tt=0;tt<2;tt++){
    #pragma unroll
    for (int r=0;r<4;r++){
      int t = tt*16 + lq*4 + r;
      size_t row = (size_t)(b*SEQ) + t0 + t;
      float s = 0.f, sq = 0.f;
      #pragma unroll
      for (int j=0;j<3;j++){
        int n = wn + j*16 + lm;
        float ov = out[row*D_MODEL + n] + acc[tt][j][r];
        acc[tt][j][r] = ov;
        out[row*D_MODEL + n] = ov;
        s += ov; sq += ov*ov;
      }
      s  += __shfl_xor(s,1);  s  += __shfl_xor(s,2);  s  += __shfl_xor(s,4);  s  += __shfl_xor(s,8);
      sq += __shfl_xor(sq,1); sq += __shfl_xor(sq,2); sq += __shfl_xor(sq,4); sq += __shfl_xor(sq,8);
      if (lm == 0){ atomicAdd(&rowsum2[t], s); atomicAdd(&rowsq2[t], sq); }
    }
  }
  if (!do_ln) return;
  __syncthreads();
  if (tid < 32){
    float mu  = rowsum2[tid]*(1.f/D_MODEL);
    float var = rowsq2[tid]*(1.f/D_MODEL) - mu*mu;
    var = var < 0.f ? 0.f : var;
    mu_s[tid] = mu;
    rs_s[tid] = rsqrtf(var + 1e-12f);
  }
  __syncthreads();
  #pragma unroll
  for (int tt=0;tt<2;tt++){
    #pragma unroll
    for (int r=0;r<4;r++){
      int t = tt*16 + lq*4 + r;
      size_t row = (size_t)(b*SEQ) + t0 + t;
      float mu = mu_s[t], rs = rs_s[t];
      #pragma unroll
      for (int j=0;j<3;j++){
        int n = wn + j*16 + lm;
        hnb[row*D_MODEL + n] = f_to_bits((acc[tt][j][r]-mu)*rs*lnw[n] + lnb[n]);
      }
    }
  }
}

extern "C" void kernel_launch(void* const* d_in, const int* in_sizes, int n_in,
                              void* d_out, int out_size, void* d_ws, size_t ws_size,
                              hipStream_t stream){
  const float* x0      = (const float*)d_in[0];
  const float* ln_w    = (const float*)d_in[1];
  const float* ln_b    = (const float*)d_in[2];
  const float* W_in    = (const float*)d_in[3];
  const float* conv_w  = (const float*)d_in[4];
  const float* conv_b  = (const float*)d_in[5];
  const float* dt_bias = (const float*)d_in[6];
  const float* A_log   = (const float*)d_in[7];
  const float* D_skip  = (const float*)d_in[8];
  const float* norm_w  = (const float*)d_in[9];
  const float* W_out   = (const float*)d_in[10];
  float* out = (float*)d_out;

  /* workspace (float units), ~91 MB */
  float* p    = (float*)d_ws;
  unsigned short* zxb = (unsigned short*)p;   p += (size_t)ROWS*ZXB_LD/2;
  float* dtraw = p;  p += (size_t)ROWS*8;
  float* cumb  = p;  p += (size_t)BATCH*NHEADS*SEQ;
  float* Dc    = p;  p += (size_t)BATCH*NHEADS*NC;
  unsigned short* ybuf = (unsigned short*)p;  p += (size_t)ROWS*D_INNER/2;
  unsigned short* hnb  = (unsigned short*)p;  p += (size_t)ROWS*D_INNER/2;  /* only D_MODEL used */
  unsigned short* Sb   = (unsigned short*)p;  p += (size_t)BATCH*NC*NHEADS*HEADDIM*D_STATE/2;
  unsigned short* Cb   = (unsigned short*)p;  p += (size_t)ROWS*D_STATE/2;
  bf16* Wt  = (bf16*)p; p += (size_t)NUM_LAYERS*NPAD_IN*D_MODEL/2;
  bf16* Wot = (bf16*)p;

  hipMemcpyAsync(out, x0, (size_t)ROWS*D_MODEL*sizeof(float),
                 hipMemcpyDeviceToDevice, stream);

  wconv_kernel<<<dim3(NPAD_IN/32, D_MODEL/32, NUM_LAYERS), dim3(32,8), 0, stream>>>(
      W_in, Wt, D_MODEL, D_IN_PROJ, NPAD_IN);
  wconv_kernel<<<dim3(NPAD_OUT/32, D_INNER/32, NUM_LAYERS), dim3(32,8), 0, stream>>>(
      W_out, Wot, D_INNER, D_MODEL, NPAD_OUT);

  /* layer-0 LayerNorm (subsequent layers' LN is fused into hinfuse_out) */
  ln_kernel<<<ROWS/4,256,0,stream>>>(out, ln_w, ln_b, hnb);

  for (int i=0;i<NUM_LAYERS;i++){
    int last = (i == NUM_LAYERS-1);
    gemm_in<<<dim3(NPAD_IN/128, ROWS/128), 256, 0, stream>>>(
        (const unsigned short*)hnb, (const unsigned short*)(Wt + (size_t)i*NPAD_IN*D_MODEL),
        zxb, dtraw, D_MODEL);
    fused_scan_kernel<<<BATCH*NC*4, 256, 0, stream>>>(
        zxb, dtraw, conv_w + (size_t)i*CONV_DIM*4, conv_b + (size_t)i*CONV_DIM,
        dt_bias+(size_t)i*NHEADS, A_log+(size_t)i*NHEADS, D_skip+(size_t)i*NHEADS,
        cumb, Dc, Cb, Sb, ybuf);
    combine_kernel<<<(BATCH*NHEADS*HEADDIM*16)/256, 256, 0, stream>>>(Sb, Dc);
    hinfuse_out_kernel<<<BATCH*NC, 512, 0, stream>>>(
        Cb, Sb, cumb, zxb, norm_w+(size_t)i*D_INNER, ybuf,
        (const unsigned short*)(Wot + (size_t)i*NPAD_OUT*D_INNER), out,
        ln_w + (size_t)(last ? i : i+1)*D_MODEL,
        ln_b + (size_t)(last ? i : i+1)*D_MODEL,
        hnb, last ? 0 : 1);
  }
}

// Round 4
// 713.832 us; speedup vs baseline: 1.0914x; 1.0752x over previous
//
#include <hip/hip_runtime.h>
#include <hip/hip_bf16.h>
#include <math.h>

#define D_MODEL 384
#define D_STATE 64
#define D_INNER 768
#define HEADDIM 96
#define NHEADS 8
#define CONV_DIM 896
#define D_IN_PROJ 1672
#define XBC_LD 896         /* bf16 xBC row stride (X 0..767, B 768..831, C 832..895) */
#define BATCH 8
#define SEQ 1024
#define ROWS (BATCH*SEQ)   /* 8192 */
#define NUM_LAYERS 6
#define NC 32              /* chunks */
#define CHUNK 32           /* timesteps per chunk */
#define NPAD_IN 1792       /* 14 * 128 */
#define NPAD_OUT 384       /* 3 * 128  */
#define VP 776             /* padded Vsh row (shorts) */

/* fragment-tile layout: 16x16 tile stored as 256 elems, lane*4 + r
   (col = lane&15, row = (lane>>4)*4 + r)  -- matches MFMA C-layout      */
#define ZFT(rt,ct) (((size_t)(rt)*48 + (ct))*256)   /* 768-col blobs (z,y) */
#define RFT(rt,ct) (((size_t)(rt)*24 + (ct))*256)   /* 384-col blob (residual) */

typedef __hip_bfloat16 bf16;
using bf16x8_t = __attribute__((ext_vector_type(8))) short;
using f32x4_t  = __attribute__((ext_vector_type(4))) float;

__device__ __forceinline__ float softplus_f(float v){
  return v > 20.f ? v : log1pf(expf(v));
}
__device__ __forceinline__ float silu_f(float v){
  return v / (1.f + expf(-v));
}
__device__ __forceinline__ float bits_to_f(unsigned short u){
  union{unsigned u32; float f;} cv; cv.u32 = ((unsigned)u)<<16; return cv.f;
}
__device__ __forceinline__ unsigned short f_to_bits(float f){
  union{bf16 b; unsigned short u;} cv; cv.b = __float2bfloat16(f); return cv.u;
}

/* ------- weight transpose + fp32->bf16, all layers batched via grid.z ---------- */
__global__ void wconv_kernel(const float* __restrict__ W, bf16* __restrict__ Wt,
                             int K, int N, int Npad){
  __shared__ float tile[32][33];
  W  += (size_t)blockIdx.z*K*N;
  Wt += (size_t)blockIdx.z*Npad*K;
  int kb = blockIdx.y*32, nb = blockIdx.x*32;
  int tx = threadIdx.x, ty = threadIdx.y;   /* 32 x 8 */
  #pragma unroll
  for (int r=0;r<32;r+=8){
    int k = kb+ty+r, n = nb+tx;
    tile[ty+r][tx] = (k<K && n<N) ? W[(size_t)k*N+n] : 0.f;
  }
  __syncthreads();
  #pragma unroll
  for (int r=0;r<32;r+=8){
    int n = nb+ty+r, k = kb+tx;
    if (n<Npad && k<K) Wt[(size_t)n*K+k] = __float2bfloat16(tile[tx][ty+r]);
  }
}

/* ---- x0 -> residual fragment blob (in d_out) ---------------------------------- */
__global__ __launch_bounds__(256) void xfrag_kernel(const float* __restrict__ x,
                                                    float* __restrict__ rf){
  const int tile = blockIdx.x*4 + (threadIdx.x>>6);   /* 12288 tiles */
  const int lane = threadIdx.x & 63;
  const int rt = tile/24, ct = tile%24;
  const int col = ct*16 + (lane&15);
  const int r0  = rt*16 + (lane>>4)*4;
  f32x4_t v;
  #pragma unroll
  for (int r=0;r<4;r++) v[r] = x[(size_t)(r0+r)*D_MODEL + col];
  *(f32x4_t*)(rf + RFT(rt,ct) + lane*4) = v;
}

/* ---------------- LayerNorm (layer 0 only): one WAVE per row of 384 -> bf16 ---- */
__global__ __launch_bounds__(256) void ln_kernel(const float* __restrict__ x, const float* __restrict__ w,
                          const float* __restrict__ b, unsigned short* __restrict__ o){
  const int wave = threadIdx.x >> 6, lane = threadIdx.x & 63;
  const int r = blockIdx.x*4 + wave;
  const float* xr = x + (size_t)r*D_MODEL;
  float2 v[3];
  float s = 0.f, sq = 0.f;
  #pragma unroll
  for (int e=0;e<3;e++){
    v[e] = *(const float2*)(xr + e*128 + lane*2);
    s  += v[e].x + v[e].y;
    sq += v[e].x*v[e].x + v[e].y*v[e].y;
  }
  #pragma unroll
  for (int off=1; off<64; off<<=1){
    s  += __shfl_xor(s, off);
    sq += __shfl_xor(sq, off);
  }
  float mu  = s*(1.f/D_MODEL);
  float var = sq*(1.f/D_MODEL) - mu*mu;
  var = var < 0.f ? 0.f : var;
  float rstd = rsqrtf(var + 1e-12f);
  unsigned short* orow = o + (size_t)r*D_MODEL;
  #pragma unroll
  for (int e=0;e<3;e++){
    int c = e*128 + lane*2;
    float2 wv = *(const float2*)(w + c);
    float2 bv = *(const float2*)(b + c);
    ushort2 ov;
    ov.x = f_to_bits((v[e].x-mu)*rstd*wv.x + bv.x);
    ov.y = f_to_bits((v[e].y-mu)*rstd*wv.y + bv.y);
    *(ushort2*)(orow + c) = ov;
  }
}

/* ------- bf16 MFMA GEMM (in-proj): z -> zfrag, xBC -> row-major, dt -> fp32 ---- */
__global__ __launch_bounds__(256) void gemm_in(
    const unsigned short* __restrict__ A,   /* M x 384 bf16, row-major */
    const unsigned short* __restrict__ Bt,  /* Npad x K bf16 (W_in transposed) */
    unsigned short* __restrict__ zfrag,     /* fragment blob, 48 col tiles */
    unsigned short* __restrict__ xbc,       /* M x XBC_LD bf16 */
    float* __restrict__ dtraw,              /* M x 8 fp32 */
    int K){
  __shared__ __align__(16) unsigned short smem[128*136];  /* 34 KB */
  unsigned short* As = smem;          /* 128*32 */
  unsigned short* Bs = smem + 4096;   /* 128*32 */
  const int tid = threadIdx.x;
  const int wave = tid >> 6, lane = tid & 63;
  const int lq = lane >> 4, lm = lane & 15;
  /* XCD swizzle: 896 blocks = 8 XCDs x 112; each XCD gets 8 full M-rows */
  const int lin = blockIdx.y*14 + blockIdx.x;
  const int nl  = (lin & 7)*112 + (lin >> 3);
  const int m0 = (nl / 14) * 128, n0 = (nl % 14) * 128;
  const int wm = (wave >> 1) * 64, wn = (wave & 1) * 64;
  f32x4_t acc[4][4];
  #pragma unroll
  for (int i=0;i<4;i++)
    #pragma unroll
    for (int j=0;j<4;j++)
      acc[i][j] = (f32x4_t){0.f,0.f,0.f,0.f};

  for (int k0 = 0; k0 < K; k0 += 32){
    if (k0) __syncthreads();
    #pragma unroll
    for (int q=0;q<2;q++){
      int o = q*4096 + wave*1024 + lane*16;
      int m = o >> 6;
      int kb = o & 63;
      const unsigned short* ga = A  + (size_t)(m0+m)*K + k0 + (kb>>1);
      __builtin_amdgcn_global_load_lds(
          (const __attribute__((address_space(1))) void*)ga,
          (__attribute__((address_space(3))) void*)((char*)As + o), 16, 0, 0);
      const unsigned short* gb = Bt + (size_t)(n0+m)*K + k0 + (kb>>1);
      __builtin_amdgcn_global_load_lds(
          (const __attribute__((address_space(1))) void*)gb,
          (__attribute__((address_space(3))) void*)((char*)Bs + o), 16, 0, 0);
    }
    __syncthreads();
    bf16x8_t af[4], bfv[4];
    #pragma unroll
    for (int i=0;i<4;i++)
      af[i]  = *(const bf16x8_t*)(As + (wm + i*16 + lm)*32 + lq*8);
    #pragma unroll
    for (int j=0;j<4;j++)
      bfv[j] = *(const bf16x8_t*)(Bs + (wn + j*16 + lm)*32 + lq*8);
    #pragma unroll
    for (int i=0;i<4;i++)
      #pragma unroll
      for (int j=0;j<4;j++)
        acc[i][j] = __builtin_amdgcn_mfma_f32_16x16x32_bf16(af[i], bfv[j], acc[i][j], 0, 0, 0);
  }

  if (n0 == 1664){
    /* dt block: local cols 0..7 are dt (fp32 direct); rest is padding */
    if ((wave & 1) == 0 && lm < 8){
      #pragma unroll
      for (int i=0;i<4;i++){
        int row = m0 + wm + i*16 + lq*4;
        #pragma unroll
        for (int r=0;r<4;r++)
          dtraw[(size_t)(row+r)*8 + lm] = acc[i][0][r];
      }
    }
    return;
  }
  if (n0 < 768){
    /* z tiles: direct fragment-blob stores, 8B/lane coalesced */
    #pragma unroll
    for (int i=0;i<4;i++){
      int rt = (m0 + wm + i*16) >> 4;
      #pragma unroll
      for (int j=0;j<4;j++){
        int ct = (n0 + wn + j*16) >> 4;
        ushort4 v4;
        v4.x = f_to_bits(acc[i][j][0]); v4.y = f_to_bits(acc[i][j][1]);
        v4.z = f_to_bits(acc[i][j][2]); v4.w = f_to_bits(acc[i][j][3]);
        *(ushort4*)(zfrag + ZFT(rt,ct) + lane*4) = v4;
      }
    }
    return;
  }
  __syncthreads();   /* xBC: row-major via LDS bounce */
  #pragma unroll
  for (int i=0;i<4;i++){
    int rl = wm + i*16 + lq*4;
    #pragma unroll
    for (int j=0;j<4;j++){
      int cl = wn + j*16 + lm;
      #pragma unroll
      for (int r=0;r<4;r++)
        smem[(rl+r)*136 + cl] = f_to_bits(acc[i][j][r]);
    }
  }
  __syncthreads();
  {
    int row = tid >> 1;
    int cbase = (tid & 1) * 64;
    size_t gb = (size_t)(m0 + row) * XBC_LD + (n0 - 768) + cbase;
    #pragma unroll
    for (int k=0;k<8;k++)
      *(bf16x8_t*)(xbc + gb + k*8) = *(const bf16x8_t*)&smem[row*136 + cbase + k*8];
  }
}

/* ==== fused conv(k=4)+silu + dt/softplus + cumsum + chunked-SSD matmuls ======== */
__global__ __launch_bounds__(256) void fused_scan_kernel(
    const unsigned short* __restrict__ xbc, const float* __restrict__ dtraw,
    const float* __restrict__ cw, const float* __restrict__ cb,
    const float* __restrict__ dt_bias, const float* __restrict__ A_log,
    const float* __restrict__ D_skip,
    float* __restrict__ cumb, float* __restrict__ Dc,
    unsigned short* __restrict__ Cb, unsigned short* __restrict__ Sb,
    unsigned short* __restrict__ yfrag){
  __shared__ __align__(16) unsigned short Ssh[35*320];   /* stage [row][col]; Msh alias */
  __shared__ __align__(16) unsigned short XshT[192*40];  /* X^T[p_local][t] */
  __shared__ __align__(16) unsigned short BshT[64*40];   /* B^T[n][t] */
  __shared__ __align__(16) unsigned short Bsh[32*72];    /* B[t][n] */
  __shared__ __align__(16) unsigned short Csh[32*72];    /* C[t][n] */
  __shared__ float dtsh[64], Lsh[64], wsh[64];
  unsigned short* Msh = Ssh;                             /* 2*32*40 ushorts, post-conv */
  const int tid = threadIdx.x;
  const int bid = blockIdx.x;
  const int hp = bid & 3, c = (bid >> 2) & 31, b = bid >> 7;
  const int h_base = hp*2;
  const int t0 = c*CHUNK;

  /* ---- dt + raw log-decay for this block's 2 heads ---- */
  if (tid < 64){
    int hi = tid >> 5, t = tid & 31;
    int hg = h_base + hi;
    float raw = dtraw[(size_t)(b*SEQ + t0 + t)*8 + hg];
    float dtv_ = softplus_f(raw + dt_bias[hg]);
    dtsh[tid] = dtv_;
    Lsh[tid]  = dtv_ * (-expf(A_log[hg]));
  }

  /* ---- stage conv input: 35 rows x (X 192 cols | B/C 128 cols), 16B loads ---- */
  {
    const size_t rowbase = (size_t)b*SEQ*XBC_LD;
    const int gX0 = h_base*96;
    for (int i = tid; i < 35*40; i += 256){
      int row = i/40, seg = i%40;
      int l = t0 - 3 + row;
      bf16x8_t v = {0,0,0,0,0,0,0,0};
      if (l >= 0){
        int col = (seg < 24) ? (gX0 + seg*8) : (768 + (seg-24)*8);
        v = *(const bf16x8_t*)(xbc + rowbase + (size_t)l*XBC_LD + col);
      }
      *(bf16x8_t*)&Ssh[row*320 + seg*8] = v;
    }
  }
  __syncthreads();

  /* ---- conv: thread-per-column, rolling 4-tap window from LDS, silu -> LDS ---- */
  #pragma unroll
  for (int it=0; it<2; it++){
    int ci = it*256 + tid;
    if (ci < 320){
      int cch = (ci < 192) ? (h_base*96 + ci) : (D_INNER - 192 + ci);  /* conv channel */
      float4 w4 = *(const float4*)(cw + cch*4);
      float bias = cb[cch];
      float v0=0.f,v1=0.f,v2=0.f,v3=0.f;
      unsigned prev = 0;
      for (int t=-3; t<32; t++){
        float nv = bits_to_f(Ssh[(t+3)*320 + ci]);
        v0=v1; v1=v2; v2=v3; v3=nv;
        if (t < 0) continue;
        float a = silu_f(bias + w4.x*v0 + w4.y*v1 + w4.z*v2 + w4.w*v3);
        unsigned short ub = f_to_bits(a);
        if (ci < 192){
          if (t & 1) *(unsigned*)&XshT[ci*40 + (t-1)] = prev | ((unsigned)ub<<16);
          else prev = ub;
        } else if (cch < CONV_DIM - D_STATE){      /* B: cch 768..831 */
          int n = cch - D_INNER;
          Bsh[t*72 + n] = ub;
          if (t & 1) *(unsigned*)&BshT[n*40 + (t-1)] = prev | ((unsigned)ub<<16);
          else prev = ub;
        } else {                                    /* C: cch 832..895 */
          Csh[t*72 + (cch - D_INNER - D_STATE)] = ub;
        }
      }
    }
  }
  __syncthreads();

  /* ---- sequential cumsum of log-decay; chunk decay products; w-scale ---- */
  if (tid < 2){
    int hg = h_base + tid;
    float L = 0.f;
    float* cbp = cumb + ((size_t)((b*NC + c)*NHEADS) + hg)*CHUNK;
    for (int t=0;t<32;t++){
      L += Lsh[tid*32+t];
      Lsh[tid*32+t] = L;
      cbp[t] = __expf(L);
    }
    Dc[(b*NHEADS + hg)*NC + c] = __expf(L);
    for (int t=0;t<32;t++)
      wsh[tid*32+t] = __expf(L - Lsh[tid*32+t]) * dtsh[tid*32+t];
  }
  __syncthreads();

  const int wave = tid >> 6, lane = tid & 63;
  const int lq = lane >> 4, lm = lane & 15;
  const f32x4_t zero = (f32x4_t){0.f,0.f,0.f,0.f};

  /* ---- waves 0,1: G = C.B^T then M~ (D-skip on diagonal); waves 2,3: Cb out ---- */
  if (wave < 2){
    f32x4_t G[2][2];
    #pragma unroll
    for (int i=0;i<2;i++){ G[i][0]=zero; G[i][1]=zero; }
    #pragma unroll
    for (int kt=0; kt<2; kt++){
      bf16x8_t ca[2], bb[2];
      #pragma unroll
      for (int ti=0;ti<2;ti++)
        ca[ti] = *(const bf16x8_t*)&Csh[(lm+ti*16)*72 + kt*32 + lq*8];
      #pragma unroll
      for (int si=0;si<2;si++)
        bb[si] = *(const bf16x8_t*)&Bsh[(lm+si*16)*72 + kt*32 + lq*8];
      #pragma unroll
      for (int ti=0;ti<2;ti++)
        #pragma unroll
        for (int si=0;si<2;si++)
          G[ti][si] = __builtin_amdgcn_mfma_f32_16x16x32_bf16(ca[ti], bb[si], G[ti][si], 0,0,0);
    }
    int hi = wave;
    float Dk = D_skip[h_base + hi];
    float Lss[2], dts[2];
    #pragma unroll
    for (int si=0;si<2;si++){ Lss[si]=Lsh[hi*32+si*16+lm]; dts[si]=dtsh[hi*32+si*16+lm]; }
    #pragma unroll
    for (int ti=0;ti<2;ti++){
      #pragma unroll
      for (int r=0;r<4;r++){
        int t = ti*16 + lq*4 + r;
        float Lt = Lsh[hi*32 + t];
        #pragma unroll
        for (int si=0;si<2;si++){
          int s = si*16 + lm;
          float m = 0.f;
          if (s <= t){
            m = G[ti][si][r]*__expf(Lt - Lss[si])*dts[si];
            if (s == t) m += Dk;
          }
          Msh[hi*1280 + t*40 + s] = f_to_bits(m);
        }
      }
    }
  } else if (hp == 0){
    int lt = tid - 128;
    for (int i = lt; i < 512; i += 128){
      int t = i >> 4, q = i & 15;
      *(ushort4*)(Cb + ((size_t)(b*SEQ) + t0 + t)*D_STATE + q*4) =
          *(const ushort4*)&Csh[t*72 + q*4];
    }
  }
  __syncthreads();

  /* ---- compute: wave -> (head hi = wave&1, pt-half = wave>>1) ---- */
  {
    int hi = wave & 1, hg = h_base + hi;
    int ptb = (wave >> 1)*3;
    const int rt0 = (b*SEQ + t0) >> 4;
    bf16x8_t mf[2];
    #pragma unroll
    for (int tt=0;tt<2;tt++)
      mf[tt] = *(const bf16x8_t*)&Msh[hi*1280 + (lm+tt*16)*40 + lq*8];
    float wv[8];
    #pragma unroll
    for (int j=0;j<8;j++) wv[j] = wsh[hi*32 + lq*8 + j];
    bf16x8_t bw[4];
    #pragma unroll
    for (int nt=0;nt<4;nt++){
      bf16x8_t raw = *(const bf16x8_t*)&BshT[(lm+nt*16)*40 + lq*8];
      #pragma unroll
      for (int j=0;j<8;j++)
        bw[nt][j] = (short)f_to_bits(bits_to_f((unsigned short)raw[j]) * wv[j]);
    }
    const size_t sbase = ((size_t)((b*NC + c)*NHEADS) + hg)*HEADDIM*D_STATE;
    #pragma unroll
    for (int pp=0; pp<3; pp++){
      int pt = ptb + pp;
      bf16x8_t xf = *(const bf16x8_t*)&XshT[(hi*96 + pt*16 + lm)*40 + lq*8];
      /* Y1 (+ D*x via diagonal) -> fragment blob, 8B/lane */
      #pragma unroll
      for (int tt=0;tt<2;tt++){
        f32x4_t a = __builtin_amdgcn_mfma_f32_16x16x32_bf16(mf[tt], xf, zero, 0,0,0);
        ushort4 y4;
        y4.x = f_to_bits(a[0]); y4.y = f_to_bits(a[1]);
        y4.z = f_to_bits(a[2]); y4.w = f_to_bits(a[3]);
        *(ushort4*)(yfrag + ZFT(rt0+tt, hg*6+pt) + lane*4) = y4;
      }
      /* S = X^T @ (w.B) */
      #pragma unroll
      for (int nt=0;nt<4;nt++){
        f32x4_t s = __builtin_amdgcn_mfma_f32_16x16x32_bf16(xf, bw[nt], zero, 0,0,0);
        #pragma unroll
        for (int r=0;r<4;r++){
          int p = pt*16 + lq*4 + r;
          Sb[sbase + (size_t)p*D_STATE + nt*16 + lm] = f_to_bits(s[r]);
        }
      }
    }
  }
}

/* ---- sequential chunk combine on bf16 S (in-place -> Hin), 4-deep prefetch ---- */
__global__ __launch_bounds__(256) void combine_kernel(
    unsigned short* __restrict__ S, const float* __restrict__ Dc){
  int g = blockIdx.x*256 + threadIdx.x;     /* (b,h,p,nq): 8*8*96*16 = 98304 */
  int nq = g & 15;
  int p  = (g >> 4) % 96;
  int h  = (g / (16*96)) & 7;
  int b  = g / (16*96*8);
  const float* Dp = Dc + (size_t)(b*NHEADS + h)*NC;
  const size_t cstride = (size_t)NHEADS*HEADDIM*D_STATE;   /* 49152 */
  size_t base = (((size_t)(b*NC)*NHEADS + h)*HEADDIM + p)*D_STATE + nq*4;
  float H0=0.f,H1=0.f,H2=0.f,H3=0.f;
  #pragma unroll 1
  for (int c=0;c<NC;c+=4){
    ushort4 s0 = *(ushort4*)(S + base);
    ushort4 s1 = *(ushort4*)(S + base +   cstride);
    ushort4 s2 = *(ushort4*)(S + base + 2*cstride);
    ushort4 s3 = *(ushort4*)(S + base + 3*cstride);
    float D;
#define CSTEP(sv, cc) \
    *(ushort4*)(S + base) = make_ushort4(f_to_bits(H0),f_to_bits(H1),f_to_bits(H2),f_to_bits(H3)); \
    D = Dp[cc]; \
    H0 = fmaf(D,H0,bits_to_f(sv.x)); H1 = fmaf(D,H1,bits_to_f(sv.y)); \
    H2 = fmaf(D,H2,bits_to_f(sv.z)); H3 = fmaf(D,H3,bits_to_f(sv.w)); \
    base += cstride;
    CSTEP(s0, c) CSTEP(s1, c+1) CSTEP(s2, c+2) CSTEP(s3, c+3)
#undef CSTEP
  }
}

/* ==== fused tail: y+cum*(C@Hin^T), silu(z) gate, RMSNorm, @W_out into residual
   fragment blob (in d_out), and next layer's LN -> hnb. Last layer: row-major. == */
__global__ __launch_bounds__(512, 2) void hinfuse_out_kernel(
    const unsigned short* __restrict__ Cb, const unsigned short* __restrict__ Hinb,
    const float* __restrict__ cumb, const unsigned short* __restrict__ zfrag,
    const float* __restrict__ nw, const unsigned short* __restrict__ yfrag,
    const unsigned short* __restrict__ Wot,   /* NPAD_OUT x D_INNER bf16 */
    float* __restrict__ outf,                 /* residual fragment blob / final out */
    const float* __restrict__ lnw, const float* __restrict__ lnb,
    unsigned short* __restrict__ hnb,         /* next-layer LN out, bf16 */
    int last){
  __shared__ __align__(16) unsigned short Vsh[32*VP];
  __shared__ float cumsh[256];
  __shared__ float rowsq[32];
  __shared__ float rowsum2[32], rowsq2[32], mu_s[32], rs_s[32];
  const int tid = threadIdx.x;
  const int c = blockIdx.x & 31, b = blockIdx.x >> 5;
  const int t0 = c*CHUNK;
  const int rt0 = (b*SEQ + t0) >> 4;
  if (tid < 256)
    cumsh[tid] = cumb[(size_t)((b*NC + c)*NHEADS)*CHUNK + tid];   /* h=tid>>5,t=tid&31 */
  if (tid < 32){ rowsq[tid] = 0.f; rowsum2[tid] = 0.f; rowsq2[tid] = 0.f; }
  __syncthreads();
  const int wave = tid >> 6, lane = tid & 63;
  const int lq = lane >> 4, lm = lane & 15;
  const f32x4_t zero = (f32x4_t){0.f,0.f,0.f,0.f};

  /* ---- phase 1: V = (y + cum*C@Hin^T) * silu(z) into Vsh; one wave per head --- */
  {
    float sql[2][4] = {};
    const int h = wave;
    const unsigned short* Hb = Hinb + ((size_t)((b*NC + c)*NHEADS) + h)*HEADDIM*D_STATE;
    bf16x8_t ca[2][2];
    #pragma unroll
    for (int tt=0;tt<2;tt++)
      #pragma unroll
      for (int kt=0;kt<2;kt++)
        ca[tt][kt] = *(const bf16x8_t*)(Cb +
            ((size_t)(b*SEQ) + t0 + tt*16 + lm)*D_STATE + kt*32 + lq*8);
    #pragma unroll
    for (int pt=0; pt<6; pt++){
      bf16x8_t hf0 = *(const bf16x8_t*)&Hb[(size_t)(lm+pt*16)*D_STATE + lq*8];
      bf16x8_t hf1 = *(const bf16x8_t*)&Hb[(size_t)(lm+pt*16)*D_STATE + 32 + lq*8];
      f32x4_t acc[2];
      ushort4 yf4[2], zf4[2];
      #pragma unroll
      for (int tt=0;tt<2;tt++){
        yf4[tt] = *(const ushort4*)(yfrag + ZFT(rt0+tt, wave*6+pt) + lane*4);
        zf4[tt] = *(const ushort4*)(zfrag + ZFT(rt0+tt, wave*6+pt) + lane*4);
        acc[tt] = __builtin_amdgcn_mfma_f32_16x16x32_bf16(ca[tt][0], hf0, zero, 0,0,0);
        acc[tt] = __builtin_amdgcn_mfma_f32_16x16x32_bf16(ca[tt][1], hf1, acc[tt], 0,0,0);
      }
      int pcol = h*HEADDIM + pt*16 + lm;
      #pragma unroll
      for (int tt=0;tt<2;tt++){
        const unsigned short* yp = (const unsigned short*)&yf4[tt];
        const unsigned short* zp = (const unsigned short*)&zf4[tt];
        #pragma unroll
        for (int r=0;r<4;r++){
          int t = tt*16 + lq*4 + r;
          float yv = bits_to_f(yp[r]) + cumsh[h*32+t]*acc[tt][r];
          float z  = bits_to_f(zp[r]);
          float v  = yv * silu_f(z);
          Vsh[t*VP + pcol] = f_to_bits(v);
          sql[tt][r] += v*v;
        }
      }
    }
    #pragma unroll
    for (int tt=0;tt<2;tt++)
      #pragma unroll
      for (int r=0;r<4;r++){
        float v = sql[tt][r];
        v += __shfl_xor(v,1); v += __shfl_xor(v,2);
        v += __shfl_xor(v,4); v += __shfl_xor(v,8);
        if (lm == 0) atomicAdd(&rowsq[tt*16 + lq*4 + r], v);
      }
  }
  __syncthreads();
  if (tid < 32) rowsq[tid] = rsqrtf(rowsq[tid]*(1.f/D_INNER) + 1e-5f);
  __syncthreads();
  /* ---- normalize V in place (RMSNorm * norm_w), bf16 -> Vsh ---- */
  for (int i=tid; i<32*192; i+=512){
    int t = i/192, q = i%192;
    ushort4 pv = *(const ushort4*)&Vsh[t*VP + q*4];
    float rms = rowsq[t];
    float4 w4 = *(const float4*)(nw + q*4);
    ushort4 o;
    o.x = f_to_bits(bits_to_f(pv.x)*rms*w4.x);
    o.y = f_to_bits(bits_to_f(pv.y)*rms*w4.y);
    o.z = f_to_bits(bits_to_f(pv.z)*rms*w4.z);
    o.w = f_to_bits(bits_to_f(pv.w)*rms*w4.w);
    *(ushort4*)&Vsh[t*VP + q*4] = o;
  }
  __syncthreads();

  /* ---- phase 2: delta(32x384) = Vsh(32x768) @ Wot^T; each wave 48 cols ---- */
  const int wn = wave*48;
  f32x4_t acc[2][3];
  #pragma unroll
  for (int i=0;i<2;i++)
    #pragma unroll
    for (int j=0;j<3;j++)
      acc[i][j] = zero;
  for (int k0=0; k0<D_INNER; k0+=32){
    bf16x8_t af[2], bfv[3];
    #pragma unroll
    for (int i=0;i<2;i++)
      af[i] = *(const bf16x8_t*)&Vsh[(i*16 + lm)*VP + k0 + lq*8];
    #pragma unroll
    for (int j=0;j<3;j++)
      bfv[j] = *(const bf16x8_t*)(Wot + (size_t)(wn + j*16 + lm)*D_INNER + k0 + lq*8);
    #pragma unroll
    for (int i=0;i<2;i++)
      #pragma unroll
      for (int j=0;j<3;j++)
        acc[i][j] = __builtin_amdgcn_mfma_f32_16x16x32_bf16(af[i], bfv[j], acc[i][j], 0,0,0);
  }

  /* ---- phase 3: residual RMW on fragment blob; LN -> hnb (or final row-major) -- */
  float ov[2][3][4];
  #pragma unroll
  for (int tt=0;tt<2;tt++)
    #pragma unroll
    for (int j=0;j<3;j++){
      f32x4_t rv = *(const f32x4_t*)(outf + RFT(rt0+tt, wave*3+j) + lane*4);
      #pragma unroll
      for (int r=0;r<4;r++) ov[tt][j][r] = rv[r] + acc[tt][j][r];
    }

  if (last){
    __syncthreads();   /* all fragment reads done before row-major writes to slab */
    #pragma unroll
    for (int tt=0;tt<2;tt++)
      #pragma unroll
      for (int r=0;r<4;r++){
        size_t row = (size_t)(b*SEQ) + t0 + tt*16 + lq*4 + r;
        #pragma unroll
        for (int j=0;j<3;j++)
          outf[row*D_MODEL + wn + j*16 + lm] = ov[tt][j][r];
      }
    return;
  }

  #pragma unroll
  for (int tt=0;tt<2;tt++)
    #pragma unroll
    for (int j=0;j<3;j++){
      f32x4_t rv;
      #pragma unroll
      for (int r=0;r<4;r++) rv[r] = ov[tt][j][r];
      *(f32x4_t*)(outf + RFT(rt0+tt, wave*3+j) + lane*4) = rv;
    }
  /* LN stats */
  #pragma unroll
  for (int tt=0;tt<2;tt++){
    #pragma unroll
    for (int r=0;r<4;r++){
      int t = tt*16 + lq*4 + r;
      float s = 0.f, sq = 0.f;
      #pragma unroll
      for (int j=0;j<3;j++){ float o = ov[tt][j][r]; s += o; sq += o*o; }
      s  += __shfl_xor(s,1);  s  += __shfl_xor(s,2);  s  += __shfl_xor(s,4);  s  += __shfl_xor(s,8);
      sq += __shfl_xor(sq,1); sq += __shfl_xor(sq,2); sq += __shfl_xor(sq,4); sq += __shfl_xor(sq,8);
      if (lm == 0){ atomicAdd(&rowsum2[t], s); atomicAdd(&rowsq2[t], sq); }
    }
  }
  __syncthreads();
  if (tid < 32){
    float mu  = rowsum2[tid]*(1.f/D_MODEL);
    float var = rowsq2[tid]*(1.f/D_MODEL) - mu*mu;
    var = var < 0.f ? 0.f : var;
    mu_s[tid] = mu;
    rs_s[tid] = rsqrtf(var + 1e-12f);
  }
  __syncthreads();
  #pragma unroll
  for (int tt=0;tt<2;tt++){
    #pragma unroll
    for (int r=0;r<4;r++){
      int t = tt*16 + lq*4 + r;
      size_t row = (size_t)(b*SEQ) + t0 + t;
      float mu = mu_s[t], rs = rs_s[t];
      #pragma unroll
      for (int j=0;j<3;j++){
        int n = wn + j*16 + lm;
        hnb[row*D_MODEL + n] = f_to_bits((ov[tt][j][r]-mu)*rs*lnw[n] + lnb[n]);
      }
    }
  }
}

extern "C" void kernel_launch(void* const* d_in, const int* in_sizes, int n_in,
                              void* d_out, int out_size, void* d_ws, size_t ws_size,
                              hipStream_t stream){
  const float* x0      = (const float*)d_in[0];
  const float* ln_w    = (const float*)d_in[1];
  const float* ln_b    = (const float*)d_in[2];
  const float* W_in    = (const float*)d_in[3];
  const float* conv_w  = (const float*)d_in[4];
  const float* conv_b  = (const float*)d_in[5];
  const float* dt_bias = (const float*)d_in[6];
  const float* A_log   = (const float*)d_in[7];
  const float* D_skip  = (const float*)d_in[8];
  const float* norm_w  = (const float*)d_in[9];
  const float* W_out   = (const float*)d_in[10];
  float* out = (float*)d_out;

  /* workspace (float units), ~85 MB */
  float* p    = (float*)d_ws;
  unsigned short* xbc   = (unsigned short*)p; p += (size_t)ROWS*XBC_LD/2;
  float* dtraw = p;  p += (size_t)ROWS*8;
  float* cumb  = p;  p += (size_t)BATCH*NHEADS*SEQ;
  float* Dc    = p;  p += (size_t)BATCH*NHEADS*NC;
  unsigned short* yfrag = (unsigned short*)p; p += (size_t)ROWS*D_INNER/2;
  unsigned short* zfrag = (unsigned short*)p; p += (size_t)ROWS*D_INNER/2;
  unsigned short* hnb   = (unsigned short*)p; p += (size_t)ROWS*D_MODEL/2;
  unsigned short* Sb    = (unsigned short*)p; p += (size_t)BATCH*NC*NHEADS*HEADDIM*D_STATE/2;
  unsigned short* Cb    = (unsigned short*)p; p += (size_t)ROWS*D_STATE/2;
  bf16* Wt  = (bf16*)p; p += (size_t)NUM_LAYERS*NPAD_IN*D_MODEL/2;
  bf16* Wot = (bf16*)p;

  wconv_kernel<<<dim3(NPAD_IN/32, D_MODEL/32, NUM_LAYERS), dim3(32,8), 0, stream>>>(
      W_in, Wt, D_MODEL, D_IN_PROJ, NPAD_IN);
  wconv_kernel<<<dim3(NPAD_OUT/32, D_INNER/32, NUM_LAYERS), dim3(32,8), 0, stream>>>(
      W_out, Wot, D_INNER, D_MODEL, NPAD_OUT);

  /* residual stream -> fragment blob inside d_out; layer-0 LN from x0 */
  xfrag_kernel<<<(ROWS/16)*24/4, 256, 0, stream>>>(x0, out);
  ln_kernel<<<ROWS/4,256,0,stream>>>(x0, ln_w, ln_b, hnb);

  for (int i=0;i<NUM_LAYERS;i++){
    int last = (i == NUM_LAYERS-1);
    gemm_in<<<dim3(NPAD_IN/128, ROWS/128), 256, 0, stream>>>(
        (const unsigned short*)hnb, (const unsigned short*)(Wt + (size_t)i*NPAD_IN*D_MODEL),
        zfrag, xbc, dtraw, D_MODEL);
    fused_scan_kernel<<<BATCH*NC*4, 256, 0, stream>>>(
        xbc, dtraw, conv_w + (size_t)i*CONV_DIM*4, conv_b + (size_t)i*CONV_DIM,
        dt_bias+(size_t)i*NHEADS, A_log+(size_t)i*NHEADS, D_skip+(size_t)i*NHEADS,
        cumb, Dc, Cb, Sb, yfrag);
    combine_kernel<<<(BATCH*NHEADS*HEADDIM*16)/256, 256, 0, stream>>>(Sb, Dc);
    hinfuse_out_kernel<<<BATCH*NC, 512, 0, stream>>>(
        Cb, Sb, cumb, zfrag, norm_w+(size_t)i*D_INNER, yfrag,
        (const unsigned short*)(Wot + (size_t)i*NPAD_OUT*D_INNER), out,
        ln_w + (size_t)(last ? i : i+1)*D_MODEL,
        ln_b + (size_t)(last ? i : i+1)*D_MODEL,
        hnb, last);
  }
}